// Round 12
// baseline (2164.288 us; speedup 1.0000x reference)
//
#include <hip/hip_runtime.h>
#include <hip/hip_bf16.h>
#include <math.h>

// Shapes: B=16, C=256, H=W=96, S=3, OUT_C=64
#define NPOS 9216
#define PERB 2359296ull        // 256*9216 elements (one [C][H*W] plane-set)

typedef unsigned short u16;
typedef __attribute__((ext_vector_type(8))) short short8;  // bf16x8 MFMA frag
typedef __attribute__((ext_vector_type(4))) float f32x4;   // MFMA acc

__device__ inline u16 bfhi(float x) {
    unsigned int b = __float_as_uint(x);
    return (u16)((b + 0x7FFFu + ((b >> 16) & 1u)) >> 16);   // RNE f32->bf16
}
__device__ inline float bf2f(u16 u) { return __uint_as_float(((unsigned int)u) << 16); }

// async global->LDS, 16B per lane (dest = uniform base + lane*16)
typedef const __attribute__((address_space(1))) void* gvp;
typedef __attribute__((address_space(3))) void* lvp;
__device__ __forceinline__ void glds16(const void* g, void* l) {
    __builtin_amdgcn_global_load_lds((gvp)g, (lvp)l, 16, 0, 0);
}

// ---------------------------------------------------------------------------
// Separable positional-encoding table: T[c][p], c=4j+r.
// pe[c][h*96+w] == T[c][w] + T[c][h];  r0: sin(p/95*f), r1: cos, r2/3: 0.
// ---------------------------------------------------------------------------
__global__ __launch_bounds__(256) void tt_kernel(float* __restrict__ T)
{
    int idx = blockIdx.x * 256 + threadIdx.x;   // 0..24575 (256c x 96p)
    int c = idx / 96, p = idx - (idx / 96) * 96;
    int j = c >> 2, r = c & 3;
    float f = expf(-(float)(2 * j) * 0.07195578415f);  // ln(10000)/128
    float x = (float)p * (1.0f / 95.0f) * f;
    T[idx] = (r == 0) ? sinf(x) : (r == 1) ? cosf(x) : 0.0f;
}

// ---------------------------------------------------------------------------
// Weight split: W[s][mat][256][256] f32 -> blocked bf16 hi/lo, XOR-swizzled.
// layout: [s][mat*2+mb][kb][128 rows][4 slots][8] with slot ^= (row>>1)&3
// ---------------------------------------------------------------------------
__global__ __launch_bounds__(256) void wsplit(
    const float* __restrict__ qw, const float* __restrict__ kw,
    const float* __restrict__ vw, u16* __restrict__ whi, u16* __restrict__ wlo)
{
    int bid = blockIdx.x;
    int s = bid / 48, rem = bid % 48;
    int mat = rem / 16, rem2 = rem % 16;
    int mb = rem2 / 8, kb = rem2 % 8;
    const float* W = ((mat == 0) ? qw : (mat == 1) ? kw : vw) + (size_t)s * 65536;
    int t = threadIdx.x;
    int m = t >> 1, kh = (t & 1) * 16;
    const float* src = W + (size_t)(mb * 128 + m) * 256 + kb * 32 + kh;
    int s0 = kh >> 3;                  // 0 or 2
    int sw = (m >> 1) & 3;
    size_t ob = (size_t)s * 196608 + (size_t)((mat * 2 + mb) * 8 + kb) * 4096
              + (size_t)m * 32;
    u16 hv[16], lv[16];
#pragma unroll
    for (int j = 0; j < 16; ++j) {
        float x = src[j];
        u16 h = bfhi(x);
        hv[j] = h;
        lv[j] = bfhi(x - bf2f(h));
    }
    *(uint4*)(whi + ob + ((s0 ^ sw) * 8))       = *(uint4*)hv;
    *(uint4*)(whi + ob + (((s0 + 1) ^ sw) * 8)) = *(uint4*)(hv + 8);
    *(uint4*)(wlo + ob + ((s0 ^ sw) * 8))       = *(uint4*)lv;
    *(uint4*)(wlo + ob + (((s0 + 1) ^ sw) * 8)) = *(uint4*)(lv + 8);
}

// ---------------------------------------------------------------------------
// Input split+transpose: src[b][256][9216] f32 -> blocked bf16 hi/lo, swizzled
// layout per batch: [tau=nb*8+kb][128 n][32 k], slot ^= (n>>1)&3
// ---------------------------------------------------------------------------
__global__ __launch_bounds__(256) void splitcvt(
    const float* __restrict__ src, u16* __restrict__ hi, u16* __restrict__ lo)
{
    __shared__ float ls[32 * 132];
    int tau = blockIdx.x;          // 0..575
    int nb = tau >> 3, kb = tau & 7;
    int b = blockIdx.y;
    const float* in = src + (size_t)b * PERB + (size_t)(kb * 32) * NPOS + nb * 128;
    int t = threadIdx.x;
#pragma unroll
    for (int i = 0; i < 4; ++i) {
        int idx = i * 256 + t;
        int r = idx >> 5, nq = (idx & 31) * 4;
        *(float4*)&ls[r * 132 + nq] = *(const float4*)&in[(size_t)r * NPOS + nq];
    }
    __syncthreads();
    int n = t >> 1, kh = (t & 1) * 16;
    int s0 = kh >> 3;
    int sw = (n >> 1) & 3;
    size_t ob = (size_t)b * PERB + (size_t)tau * 4096 + (size_t)n * 32;
    u16 hv[16], lv[16];
#pragma unroll
    for (int j = 0; j < 16; ++j) {
        float x = ls[(kh + j) * 132 + n];
        u16 h = bfhi(x);
        hv[j] = h;
        lv[j] = bfhi(x - bf2f(h));
    }
    *(uint4*)(hi + ob + ((s0 ^ sw) * 8))       = *(uint4*)hv;
    *(uint4*)(hi + ob + (((s0 + 1) ^ sw) * 8)) = *(uint4*)(hv + 8);
    *(uint4*)(lo + ob + ((s0 ^ sw) * 8))       = *(uint4*)lv;
    *(uint4*)(lo + ob + (((s0 + 1) ^ sw) * 8)) = *(uint4*)(lv + 8);
}

// ---------------------------------------------------------------------------
// MFMA QKV GEMM, split-bf16 — m97 structure (single-buffered 32KB LDS, two
// barriers/K-step, 3 blocks/CU) + vectorized epilogue via per-wave LDS bounce.
// ---------------------------------------------------------------------------
__global__ __launch_bounds__(256, 3) void gemm_qkv_mfma(
    const u16* __restrict__ whi, const u16* __restrict__ wlo,
    const u16* __restrict__ b1hi, const u16* __restrict__ b1lo,
    const u16* __restrict__ b2hi, const u16* __restrict__ b2lo,
    const float* __restrict__ qb, const float* __restrict__ kbias,
    const float* __restrict__ vb, const float* __restrict__ wvis,
    const float* __restrict__ wir, const float* __restrict__ Ttab,
    float* __restrict__ qo, float* __restrict__ ko, float* __restrict__ vo)
{
    __shared__ u16 AH[4096], AL[4096], BH[4096], BL[4096];   // 32KB staging
    __shared__ float SB[4][16][68];                          // 17KB epilogue

    int t = threadIdx.x;
    // bijective XCD-chunk swizzle: 432 = 54*8; consecutive roles share an XCD
    int d = blockIdx.x + 6 * blockIdx.y;           // 0..431 (dispatch order)
    int role = (d & 7) * 54 + (d >> 3);
    int mat = role / 144, rem = role - mat * 144;
    int bn = rem >> 1, mtile = rem & 1;            // mtile pair adjacent roles
    int b = blockIdx.z;

    const u16* gBh = ((mat == 0) ? b1hi : b2hi) + (size_t)b * PERB + (size_t)bn * 32768;
    const u16* gBl = ((mat == 0) ? b1lo : b2lo) + (size_t)b * PERB + (size_t)bn * 32768;
    const u16* gAh = whi + (size_t)(mat * 2 + mtile) * 32768;
    const u16* gAl = wlo + (size_t)(mat * 2 + mtile) * 32768;
    int wv = t >> 6;
    int wm = t >> 7, wn = (t >> 6) & 1;
    int rr = t & 15, gq = (t >> 4) & 3;

    // f-independent swizzled frag base offsets (u16 units); frag f adds f*512
    int sxor = (gq ^ ((rr >> 1) & 3)) * 8;
    int offA0 = (wm * 64 + rr) * 32 + sxor;
    int offB0 = (wn * 64 + rr) * 32 + sxor;

    f32x4 acc[4][4];
#pragma unroll
    for (int i = 0; i < 4; ++i)
#pragma unroll
        for (int j = 0; j < 4; ++j) acc[i][j] = (f32x4){0.f, 0.f, 0.f, 0.f};

    for (int kq = 0; kq < 8; ++kq) {
        {   // stage A+B tile (32KB, 8 x glds16 per thread, linear dest)
            const u16* sah = gAh + kq * 4096 + t * 8;
            const u16* sal = gAl + kq * 4096 + t * 8;
            const u16* sbh = gBh + kq * 4096 + t * 8;
            const u16* sbl = gBl + kq * 4096 + t * 8;
            glds16(sah,        &AH[t * 8]);
            glds16(sah + 2048, &AH[t * 8 + 2048]);
            glds16(sal,        &AL[t * 8]);
            glds16(sal + 2048, &AL[t * 8 + 2048]);
            glds16(sbh,        &BH[t * 8]);
            glds16(sbh + 2048, &BH[t * 8 + 2048]);
            glds16(sbl,        &BL[t * 8]);
            glds16(sbl + 2048, &BL[t * 8 + 2048]);
        }
        __syncthreads();       // compiler drains vmcnt here (m97 structure)

        short8 bh[4], bl[4];
#pragma unroll
        for (int r = 0; r < 4; ++r) {
            bh[r] = *(const short8*)(&BH[offB0 + r * 512]);
            bl[r] = *(const short8*)(&BL[offB0 + r * 512]);
        }
#pragma unroll
        for (int f = 0; f < 4; ++f) {
            short8 ah = *(const short8*)(&AH[offA0 + f * 512]);
            short8 al = *(const short8*)(&AL[offA0 + f * 512]);
#pragma unroll
            for (int r = 0; r < 4; ++r) {
                acc[f][r] = __builtin_amdgcn_mfma_f32_16x16x32_bf16(ah, bh[r], acc[f][r], 0, 0, 0);
                acc[f][r] = __builtin_amdgcn_mfma_f32_16x16x32_bf16(ah, bl[r], acc[f][r], 0, 0, 0);
                acc[f][r] = __builtin_amdgcn_mfma_f32_16x16x32_bf16(al, bh[r], acc[f][r], 0, 0, 0);
            }
        }
        __syncthreads();       // protect LDS overwrite by next K-step
    }

    // ---- vectorized epilogue: per-wave LDS bounce, float4 stores ----
    const float* wmap = ((mat == 0) ? wvis : wir) + (size_t)b * NPOS;
    const float* bias = (mat == 0) ? qb : (mat == 1) ? kbias : vb;
    float* outp = ((mat == 0) ? qo : (mat == 1) ? ko : vo) + (size_t)b * PERB;
    bool addpe = (mat != 2);

    int lane = t & 63;
    int lrow = lane >> 2;           // 0..15 (o-row within 16-slab)
    int lq   = lane & 3;            // col quarter
    int base_n = bn * 128 + wn * 64;

#pragma unroll
    for (int f = 0; f < 4; ++f) {
        // scatter this wave's 16x64 acc slab into SB (2-way banks = free)
#pragma unroll
        for (int r = 0; r < 4; ++r)
#pragma unroll
            for (int ri = 0; ri < 4; ++ri)
                SB[wv][gq * 4 + ri][r * 16 + rr] = acc[f][r][ri];
        // gather rows: lane owns (o = base_o + lrow, n = base_n + lq*16 + 4q)
        int o = mtile * 128 + wm * 64 + f * 16 + lrow;
        float bo = bias[o];
        const float* tro = Ttab + o * 96;
        float* orow = outp + (size_t)o * NPOS;
#pragma unroll
        for (int qd = 0; qd < 4; ++qd) {
            int c0 = lq * 16 + qd * 4;
            int n = base_n + c0;
            float4 v4 = *(float4*)&SB[wv][lrow][c0];
            float4 s4 = *(const float4*)&wmap[n];
            float4 o4;
            if (addpe) {
                int hh = n / 96, ww = n - hh * 96;   // quad never crosses a row
                float4 pw4 = *(const float4*)&tro[ww];
                float ph = tro[hh];
                o4.x = v4.x * s4.x + bo + pw4.x + ph;
                o4.y = v4.y * s4.y + bo + pw4.y + ph;
                o4.z = v4.z * s4.z + bo + pw4.z + ph;
                o4.w = v4.w * s4.w + bo + pw4.w + ph;
            } else {
                o4.x = v4.x * s4.x + bo;
                o4.y = v4.y * s4.y + bo;
                o4.z = v4.z * s4.z + bo;
                o4.w = v4.w * s4.w + bo;
            }
            *(float4*)&orow[n] = o4;
        }
        // next f reuses SB; wave-internal LDS ordering handles the hazard
    }
}

// ---------------------------------------------------------------------------
// Attention per (b,c): pitch-101 LDS (2-way banks = free) + v prefetched into
// registers at kernel start (HBM latency hidden under QK+softmax).
// R1 = q then attn; R2 = k then v.  Contiguous f32 output (coalesced).
// ---------------------------------------------------------------------------
__global__ __launch_bounds__(256) void attn_kernel(
    const float* __restrict__ q, const float* __restrict__ k,
    const float* __restrict__ v, float* __restrict__ fused)
{
    __shared__ float R1[96 * 101];  // q, later attn
    __shared__ float R2[96 * 101];  // k, later v

    int t  = threadIdx.x;
    int bc = blockIdx.x;
    const size_t base = (size_t)bc * NPOS;

    // prefetch v into regs (9 float4/thread, consumed after softmax)
    float4 vreg[9];
#pragma unroll
    for (int i = 0; i < 9; ++i) {
        int f = t + i * 256;
        int r = f / 24, w4 = (f % 24) * 4;
        vreg[i] = *(const float4*)(v + base + r * 96 + w4);
    }

    for (int f = t; f < 96 * 24; f += 256) {
        int r = f / 24, w4 = (f % 24) * 4;
        *(float4*)(R1 + r * 101 + w4) = *(const float4*)(q + base + r * 96 + w4);
        *(float4*)(R2 + r * 101 + w4) = *(const float4*)(k + base + r * 96 + w4);
    }
    __syncthreads();

    int tx = t & 15, ty = t >> 4;
    int h0 = ty * 6, g0 = tx * 6;

    float acc[6][6];
#pragma unroll
    for (int i = 0; i < 6; ++i)
#pragma unroll
        for (int j = 0; j < 6; ++j) acc[i][j] = 0.0f;

    for (int w4 = 0; w4 < 24; ++w4) {
        float4 qv[6], kv[6];
#pragma unroll
        for (int i = 0; i < 6; ++i) qv[i] = *(const float4*)(R1 + (h0 + i) * 101 + w4 * 4);
#pragma unroll
        for (int j = 0; j < 6; ++j) kv[j] = *(const float4*)(R2 + (g0 + j) * 101 + w4 * 4);
#pragma unroll
        for (int i = 0; i < 6; ++i)
#pragma unroll
            for (int j = 0; j < 6; ++j) {
                acc[i][j] = fmaf(qv[i].x, kv[j].x, acc[i][j]);
                acc[i][j] = fmaf(qv[i].y, kv[j].y, acc[i][j]);
                acc[i][j] = fmaf(qv[i].z, kv[j].z, acc[i][j]);
                acc[i][j] = fmaf(qv[i].w, kv[j].w, acc[i][j]);
            }
    }

#pragma unroll
    for (int i = 0; i < 6; ++i) {
        float m = acc[i][0];
#pragma unroll
        for (int j = 1; j < 6; ++j) m = fmaxf(m, acc[i][j]);
        for (int d = 1; d < 16; d <<= 1) m = fmaxf(m, __shfl_xor(m, d));
        float s = 0.0f;
#pragma unroll
        for (int j = 0; j < 6; ++j) {
            acc[i][j] = __expf(acc[i][j] - m);
            s += acc[i][j];
        }
        for (int d = 1; d < 16; d <<= 1) s += __shfl_xor(s, d);
        float inv = 1.0f / s;
#pragma unroll
        for (int j = 0; j < 6; ++j) acc[i][j] *= inv;
    }

    __syncthreads();               // all QK reads of R1/R2 complete
    // attn -> R1; v regs -> R2
#pragma unroll
    for (int i = 0; i < 6; ++i)
#pragma unroll
        for (int j = 0; j < 6; ++j) R1[(h0 + i) * 101 + g0 + j] = acc[i][j];
#pragma unroll
    for (int i = 0; i < 9; ++i) {
        int f = t + i * 256;
        int r = f / 24, w4 = (f % 24) * 4;
        *(float4*)(R2 + r * 101 + w4) = vreg[i];
    }
    __syncthreads();

    int w0 = tx * 6;
    float outv[6][6];
#pragma unroll
    for (int i = 0; i < 6; ++i)
#pragma unroll
        for (int j = 0; j < 6; ++j) outv[i][j] = 0.0f;

    for (int g4 = 0; g4 < 24; ++g4) {
        float4 av[6];
#pragma unroll
        for (int i = 0; i < 6; ++i) av[i] = *(const float4*)(R1 + (h0 + i) * 101 + g4 * 4);
#pragma unroll
        for (int gg = 0; gg < 4; ++gg) {
            int g = g4 * 4 + gg;
            float vr[6];
#pragma unroll
            for (int j = 0; j < 6; ++j) vr[j] = R2[g * 101 + w0 + j];
#pragma unroll
            for (int i = 0; i < 6; ++i) {
                float a = (gg == 0) ? av[i].x : (gg == 1) ? av[i].y : (gg == 2) ? av[i].z : av[i].w;
#pragma unroll
                for (int j = 0; j < 6; ++j) outv[i][j] = fmaf(a, vr[j], outv[i][j]);
            }
        }
    }

#pragma unroll
    for (int i = 0; i < 6; ++i) {
        float* op = fused + base + (size_t)(h0 + i) * 96 + w0;
#pragma unroll
        for (int j = 0; j < 6; ++j) op[j] = outv[i][j];
    }
}

// ---------------------------------------------------------------------------
// Final projection: out[b][o][n] = sum_c proj_w[o][c]*fused[b][c][n] + pb[o]
// ---------------------------------------------------------------------------
__global__ __launch_bounds__(256) void proj_kernel(
    const float* __restrict__ fused, const float* __restrict__ pw,
    const float* __restrict__ pb, float* __restrict__ out)
{
    __shared__ float As[16 * 68];
    __shared__ float Bs[16 * 128];

    int t  = threadIdx.x;
    int n0 = blockIdx.x * 128;
    int b  = blockIdx.y;
    const float* B = fused + (size_t)b * PERB;
    int tx = t & 15, ty = t >> 4;

    float acc[4][8];
#pragma unroll
    for (int i = 0; i < 4; ++i)
#pragma unroll
        for (int j = 0; j < 8; ++j) acc[i][j] = 0.0f;

    for (int k0 = 0; k0 < 256; k0 += 16) {
        {
            int m = t >> 2, c4 = (t & 3) * 4;
            float4 av = *(const float4*)(pw + (size_t)m * 256 + k0 + c4);
            As[(c4 + 0) * 68 + m] = av.x;
            As[(c4 + 1) * 68 + m] = av.y;
            As[(c4 + 2) * 68 + m] = av.z;
            As[(c4 + 3) * 68 + m] = av.w;
        }
#pragma unroll
        for (int l = 0; l < 2; ++l) {
            int f = t + l * 256;
            int c = f >> 5, n4 = (f & 31) * 4;
            *(float4*)(Bs + c * 128 + n4) =
                *(const float4*)(B + (size_t)(k0 + c) * NPOS + n0 + n4);
        }
        __syncthreads();
#pragma unroll
        for (int kk = 0; kk < 16; ++kk) {
            float a[4], bb[8];
            *(float4*)(&a[0])  = *(const float4*)(As + kk * 68 + ty * 4);
            *(float4*)(&bb[0]) = *(const float4*)(Bs + kk * 128 + tx * 8);
            *(float4*)(&bb[4]) = *(const float4*)(Bs + kk * 128 + tx * 8 + 4);
#pragma unroll
            for (int i = 0; i < 4; ++i)
#pragma unroll
                for (int j = 0; j < 8; ++j)
                    acc[i][j] = fmaf(a[i], bb[j], acc[i][j]);
        }
        __syncthreads();
    }

    int n = n0 + tx * 8;
#pragma unroll
    for (int i = 0; i < 4; ++i) {
        int o = ty * 4 + i;
        float bias = pb[o];
        float vals[8];
#pragma unroll
        for (int j = 0; j < 8; ++j) vals[j] = acc[i][j] + bias;
        float* op = out + ((size_t)b * 64 + o) * NPOS + n;
        *(float4*)(op)     = *(float4*)(&vals[0]);
        *(float4*)(op + 4) = *(float4*)(&vals[4]);
    }
}

// ---------------------------------------------------------------------------
extern "C" void kernel_launch(void* const* d_in, const int* in_sizes, int n_in,
                              void* d_out, int out_size, void* d_ws, size_t ws_size,
                              hipStream_t stream)
{
    const float* x1   = (const float*)d_in[0];
    const float* x2   = (const float*)d_in[1];
    const float* wvis = (const float*)d_in[2];
    const float* wir  = (const float*)d_in[3];
    const float* qw   = (const float*)d_in[4];
    const float* qb   = (const float*)d_in[5];
    const float* kw   = (const float*)d_in[6];
    const float* kb   = (const float*)d_in[7];
    const float* vw   = (const float*)d_in[8];
    const float* vb   = (const float*)d_in[9];
    const float* pw   = (const float*)d_in[10];
    const float* pb   = (const float*)d_in[11];
    float* out = (float*)d_out;

    float* ws = (float*)d_ws;
    size_t F = ws_size / 4;
    size_t fixed = 700000;   // T table (24576) + weights (~590K f32-equiv)
    size_t avail = (F > fixed) ? (F - fixed) : 0;
    int G = (int)(avail / (6 * PERB));
    if (G < 1) G = 1;
    if (G > 8) G = 8;

    float* ttab  = ws;                       // 24576 floats
    float* qbuf  = ws + 24576;
    float* kbuf  = qbuf + (size_t)G * PERB;
    float* vbuf  = kbuf + (size_t)G * PERB;
    float* fbuf  = vbuf + (size_t)G * PERB;
    u16*   b1hi  = (u16*)(fbuf + (size_t)G * PERB);
    u16*   b1lo  = b1hi + (size_t)G * PERB;
    u16*   b2hi  = b1lo + (size_t)G * PERB;
    u16*   b2lo  = b2hi + (size_t)G * PERB;
    u16*   whiP  = b2lo + (size_t)G * PERB;
    u16*   wloP  = whiP + 589824;

    tt_kernel<<<dim3(96), 256, 0, stream>>>(ttab);
    wsplit<<<dim3(144), 256, 0, stream>>>(qw, kw, vw, whiP, wloP);

    for (int b0 = 0; b0 < 16; b0 += G) {
        int g = (16 - b0 < G) ? (16 - b0) : G;
        splitcvt<<<dim3(576, g), 256, 0, stream>>>(x1 + (size_t)b0 * PERB, b1hi, b1lo);
        splitcvt<<<dim3(576, g), 256, 0, stream>>>(x2 + (size_t)b0 * PERB, b2hi, b2lo);
        for (int s = 0; s < 3; ++s) {
            if (s > 0)
                splitcvt<<<dim3(576, g), 256, 0, stream>>>(fbuf, b1hi, b1lo);
            const u16* xh = (s == 0) ? b2hi : b1hi;
            const u16* xl = (s == 0) ? b2lo : b1lo;
            gemm_qkv_mfma<<<dim3(6, 72, g), 256, 0, stream>>>(
                whiP + (size_t)s * 196608, wloP + (size_t)s * 196608,
                b1hi, b1lo, xh, xl,
                qb + (size_t)s * 256, kb + (size_t)s * 256, vb + (size_t)s * 256,
                wvis + (size_t)b0 * NPOS, wir + (size_t)b0 * NPOS,
                ttab, qbuf, kbuf, vbuf);
            attn_kernel<<<dim3(256 * g), 256, 0, stream>>>(qbuf, kbuf, vbuf, fbuf);
        }
        proj_kernel<<<dim3(72, g), 256, 0, stream>>>(
            fbuf, pw, pb, out + (size_t)b0 * 64 * NPOS);
    }
}

// Round 13
// 1926.393 us; speedup vs baseline: 1.1235x; 1.1235x over previous
//
#include <hip/hip_runtime.h>
#include <hip/hip_bf16.h>
#include <math.h>

// Shapes: B=16, C=256, H=W=96, S=3, OUT_C=64
#define NPOS 9216
#define PERB 2359296ull        // 256*9216 elements (one [C][H*W] plane-set)

typedef unsigned short u16;
typedef __attribute__((ext_vector_type(8))) short short8;  // bf16x8 MFMA frag
typedef __attribute__((ext_vector_type(4))) float f32x4;   // MFMA acc

__device__ inline u16 bfhi(float x) {
    unsigned int b = __float_as_uint(x);
    return (u16)((b + 0x7FFFu + ((b >> 16) & 1u)) >> 16);   // RNE f32->bf16
}
__device__ inline float bf2f(u16 u) { return __uint_as_float(((unsigned int)u) << 16); }

// async global->LDS, 16B per lane (dest = uniform base + lane*16)
typedef const __attribute__((address_space(1))) void* gvp;
typedef __attribute__((address_space(3))) void* lvp;
__device__ __forceinline__ void glds16(const void* g, void* l) {
    __builtin_amdgcn_global_load_lds((gvp)g, (lvp)l, 16, 0, 0);
}

// ---------------------------------------------------------------------------
// Separable positional-encoding table: T[c][p], c=4j+r.
// pe[c][h*96+w] == T[c][w] + T[c][h];  r0: sin(p/95*f), r1: cos, r2/3: 0.
// ---------------------------------------------------------------------------
__global__ __launch_bounds__(256) void tt_kernel(float* __restrict__ T)
{
    int idx = blockIdx.x * 256 + threadIdx.x;   // 0..24575 (256c x 96p)
    int c = idx / 96, p = idx - (idx / 96) * 96;
    int j = c >> 2, r = c & 3;
    float f = expf(-(float)(2 * j) * 0.07195578415f);  // ln(10000)/128
    float x = (float)p * (1.0f / 95.0f) * f;
    T[idx] = (r == 0) ? sinf(x) : (r == 1) ? cosf(x) : 0.0f;
}

// ---------------------------------------------------------------------------
// Weight split: W[s][mat][256][256] f32 -> blocked bf16 hi/lo, XOR-swizzled.
// layout: [s][mat*2+mb][kb][128 rows][4 slots][8] with slot ^= (row>>1)&3
// ---------------------------------------------------------------------------
__global__ __launch_bounds__(256) void wsplit(
    const float* __restrict__ qw, const float* __restrict__ kw,
    const float* __restrict__ vw, u16* __restrict__ whi, u16* __restrict__ wlo)
{
    int bid = blockIdx.x;
    int s = bid / 48, rem = bid % 48;
    int mat = rem / 16, rem2 = rem % 16;
    int mb = rem2 / 8, kb = rem2 % 8;
    const float* W = ((mat == 0) ? qw : (mat == 1) ? kw : vw) + (size_t)s * 65536;
    int t = threadIdx.x;
    int m = t >> 1, kh = (t & 1) * 16;
    const float* src = W + (size_t)(mb * 128 + m) * 256 + kb * 32 + kh;
    int s0 = kh >> 3;                  // 0 or 2
    int sw = (m >> 1) & 3;
    size_t ob = (size_t)s * 196608 + (size_t)((mat * 2 + mb) * 8 + kb) * 4096
              + (size_t)m * 32;
    u16 hv[16], lv[16];
#pragma unroll
    for (int j = 0; j < 16; ++j) {
        float x = src[j];
        u16 h = bfhi(x);
        hv[j] = h;
        lv[j] = bfhi(x - bf2f(h));
    }
    *(uint4*)(whi + ob + ((s0 ^ sw) * 8))       = *(uint4*)hv;
    *(uint4*)(whi + ob + (((s0 + 1) ^ sw) * 8)) = *(uint4*)(hv + 8);
    *(uint4*)(wlo + ob + ((s0 ^ sw) * 8))       = *(uint4*)lv;
    *(uint4*)(wlo + ob + (((s0 + 1) ^ sw) * 8)) = *(uint4*)(lv + 8);
}

// ---------------------------------------------------------------------------
// MFMA QKV GEMM, split-bf16 — m97 structure; A (weights) via glds16 from the
// blocked/swizzled u16 layout; B staged DIRECTLY from the f32 source plane
// (x or fused) with inline hi/lo split + transpose (lane-coalesced dword
// loads -> bfhi/lo cvt -> swizzled ds_write_b128).  Eliminates splitcvt.
// ---------------------------------------------------------------------------
__global__ __launch_bounds__(256, 3) void gemm_qkv_mfma(
    const u16* __restrict__ whi, const u16* __restrict__ wlo,
    const float* __restrict__ srcq, const float* __restrict__ srckv,
    const float* __restrict__ qb, const float* __restrict__ kbias,
    const float* __restrict__ vb, const float* __restrict__ wvis,
    const float* __restrict__ wir, const float* __restrict__ Ttab,
    float* __restrict__ qo, float* __restrict__ ko, float* __restrict__ vo)
{
    __shared__ u16 AH[4096], AL[4096], BH[4096], BL[4096];   // 32KB staging
    __shared__ float SB[4][16][68];                          // 17KB epilogue

    int t = threadIdx.x;
    // bijective XCD-chunk swizzle: 432 = 54*8; consecutive roles share an XCD
    int d = blockIdx.x + 6 * blockIdx.y;           // 0..431 (dispatch order)
    int role = (d & 7) * 54 + (d >> 3);
    int mat = role / 144, rem = role - mat * 144;
    int bn = rem >> 1, mtile = rem & 1;            // mtile pair adjacent roles
    int b = blockIdx.z;

    const float* gB = ((mat == 0) ? srcq : srckv) + (size_t)b * PERB + bn * 128;
    const u16* gAh = whi + (size_t)(mat * 2 + mtile) * 32768;
    const u16* gAl = wlo + (size_t)(mat * 2 + mtile) * 32768;
    int wv = t >> 6;
    int wm = t >> 7, wn = (t >> 6) & 1;
    int rr = t & 15, gq = (t >> 4) & 3;

    // f-independent swizzled frag base offsets (u16 units); frag f adds f*512
    int sxor = (gq ^ ((rr >> 1) & 3)) * 8;
    int offA0 = (wm * 64 + rr) * 32 + sxor;
    int offB0 = (wn * 64 + rr) * 32 + sxor;

    // B-staging mapping: thread covers (n = t&127, k = (t>>7)*16 + j)
    int bn_ = t & 127, bkh = t >> 7;
    int key = (bn_ >> 1) & 3;
    int wr0 = bn_ * 32 + (((bkh * 2)     ^ key) * 8);
    int wr1 = bn_ * 32 + (((bkh * 2 + 1) ^ key) * 8);
    const float* bp = gB + (size_t)(bkh * 16) * NPOS + bn_;

    f32x4 acc[4][4];
#pragma unroll
    for (int i = 0; i < 4; ++i)
#pragma unroll
        for (int j = 0; j < 4; ++j) acc[i][j] = (f32x4){0.f, 0.f, 0.f, 0.f};

    // prologue: load B tile 0 into regs (coalesced dword per lane)
    float xv[16];
#pragma unroll
    for (int j = 0; j < 16; ++j) xv[j] = bp[(size_t)j * NPOS];

    for (int kq = 0; kq < 8; ++kq) {
        {   // stage A tile via glds16 (pre-swizzled blocked layout)
            const u16* sah = gAh + kq * 4096 + t * 8;
            const u16* sal = gAl + kq * 4096 + t * 8;
            glds16(sah,        &AH[t * 8]);
            glds16(sah + 2048, &AH[t * 8 + 2048]);
            glds16(sal,        &AL[t * 8]);
            glds16(sal + 2048, &AL[t * 8 + 2048]);
        }
        {   // convert current B regs -> swizzled LDS (hi/lo)
            u16 hv[16], lv[16];
#pragma unroll
            for (int j = 0; j < 16; ++j) {
                float x = xv[j];
                u16 h = bfhi(x);
                hv[j] = h;
                lv[j] = bfhi(x - bf2f(h));
            }
            *(uint4*)(&BH[wr0]) = *(uint4*)hv;
            *(uint4*)(&BH[wr1]) = *(uint4*)(hv + 8);
            *(uint4*)(&BL[wr0]) = *(uint4*)lv;
            *(uint4*)(&BL[wr1]) = *(uint4*)(lv + 8);
        }
        __syncthreads();    // drains glds16 (vmcnt) + ds_writes (lgkm)

        // issue next-tile B loads; latency hides under MFMA + barrier
        if (kq < 7) {
#pragma unroll
            for (int j = 0; j < 16; ++j)
                xv[j] = bp[(size_t)((kq + 1) * 32 + j) * NPOS];
        }

        short8 bh[4], bl[4];
#pragma unroll
        for (int r = 0; r < 4; ++r) {
            bh[r] = *(const short8*)(&BH[offB0 + r * 512]);
            bl[r] = *(const short8*)(&BL[offB0 + r * 512]);
        }
#pragma unroll
        for (int f = 0; f < 4; ++f) {
            short8 ah = *(const short8*)(&AH[offA0 + f * 512]);
            short8 al = *(const short8*)(&AL[offA0 + f * 512]);
#pragma unroll
            for (int r = 0; r < 4; ++r) {
                acc[f][r] = __builtin_amdgcn_mfma_f32_16x16x32_bf16(ah, bh[r], acc[f][r], 0, 0, 0);
                acc[f][r] = __builtin_amdgcn_mfma_f32_16x16x32_bf16(ah, bl[r], acc[f][r], 0, 0, 0);
                acc[f][r] = __builtin_amdgcn_mfma_f32_16x16x32_bf16(al, bh[r], acc[f][r], 0, 0, 0);
            }
        }
        __syncthreads();    // protect LDS overwrite by next K-step
    }

    // ---- vectorized epilogue: per-wave LDS bounce, float4 stores ----
    const float* wmap = ((mat == 0) ? wvis : wir) + (size_t)b * NPOS;
    const float* bias = (mat == 0) ? qb : (mat == 1) ? kbias : vb;
    float* outp = ((mat == 0) ? qo : (mat == 1) ? ko : vo) + (size_t)b * PERB;
    bool addpe = (mat != 2);

    int lane = t & 63;
    int lrow = lane >> 2;           // 0..15 (o-row within 16-slab)
    int lq   = lane & 3;            // col quarter
    int base_n = bn * 128 + wn * 64;

#pragma unroll
    for (int f = 0; f < 4; ++f) {
        // scatter this wave's 16x64 acc slab into SB (2-way banks = free)
#pragma unroll
        for (int r = 0; r < 4; ++r)
#pragma unroll
            for (int ri = 0; ri < 4; ++ri)
                SB[wv][gq * 4 + ri][r * 16 + rr] = acc[f][r][ri];
        // gather rows: lane owns (o = base_o + lrow, n = base_n + lq*16 + 4q)
        int o = mtile * 128 + wm * 64 + f * 16 + lrow;
        float bo = bias[o];
        const float* tro = Ttab + o * 96;
        float* orow = outp + (size_t)o * NPOS;
#pragma unroll
        for (int qd = 0; qd < 4; ++qd) {
            int c0 = lq * 16 + qd * 4;
            int n = base_n + c0;
            float4 v4 = *(float4*)&SB[wv][lrow][c0];
            float4 s4 = *(const float4*)&wmap[n];
            float4 o4;
            if (addpe) {
                int hh = n / 96, ww = n - hh * 96;   // quad never crosses a row
                float4 pw4 = *(const float4*)&tro[ww];
                float ph = tro[hh];
                o4.x = v4.x * s4.x + bo + pw4.x + ph;
                o4.y = v4.y * s4.y + bo + pw4.y + ph;
                o4.z = v4.z * s4.z + bo + pw4.z + ph;
                o4.w = v4.w * s4.w + bo + pw4.w + ph;
            } else {
                o4.x = v4.x * s4.x + bo;
                o4.y = v4.y * s4.y + bo;
                o4.z = v4.z * s4.z + bo;
                o4.w = v4.w * s4.w + bo;
            }
            *(float4*)&orow[n] = o4;
        }
        // next f reuses SB; wave-internal LDS ordering handles the hazard
    }
}

// ---------------------------------------------------------------------------
// Attention per (b,c): pitch-101 LDS (<=2-way banks).  R1 = q then attn;
// R2 = k then v (v staged after softmax).  Contiguous f32 output.
// ---------------------------------------------------------------------------
__global__ __launch_bounds__(256) void attn_kernel(
    const float* __restrict__ q, const float* __restrict__ k,
    const float* __restrict__ v, float* __restrict__ fused)
{
    __shared__ float R1[96 * 101];  // q, later attn
    __shared__ float R2[96 * 101];  // k, later v

    int t  = threadIdx.x;
    int bc = blockIdx.x;
    const size_t base = (size_t)bc * NPOS;

    for (int f = t; f < 96 * 24; f += 256) {
        int r = f / 24, w4 = (f % 24) * 4;
        *(float4*)(R1 + r * 101 + w4) = *(const float4*)(q + base + r * 96 + w4);
        *(float4*)(R2 + r * 101 + w4) = *(const float4*)(k + base + r * 96 + w4);
    }
    __syncthreads();

    int tx = t & 15, ty = t >> 4;
    int h0 = ty * 6, g0 = tx * 6;

    float acc[6][6];
#pragma unroll
    for (int i = 0; i < 6; ++i)
#pragma unroll
        for (int j = 0; j < 6; ++j) acc[i][j] = 0.0f;

    for (int w4 = 0; w4 < 24; ++w4) {
        float4 qv[6], kv[6];
#pragma unroll
        for (int i = 0; i < 6; ++i) qv[i] = *(const float4*)(R1 + (h0 + i) * 101 + w4 * 4);
#pragma unroll
        for (int j = 0; j < 6; ++j) kv[j] = *(const float4*)(R2 + (g0 + j) * 101 + w4 * 4);
#pragma unroll
        for (int i = 0; i < 6; ++i)
#pragma unroll
            for (int j = 0; j < 6; ++j) {
                acc[i][j] = fmaf(qv[i].x, kv[j].x, acc[i][j]);
                acc[i][j] = fmaf(qv[i].y, kv[j].y, acc[i][j]);
                acc[i][j] = fmaf(qv[i].z, kv[j].z, acc[i][j]);
                acc[i][j] = fmaf(qv[i].w, kv[j].w, acc[i][j]);
            }
    }

#pragma unroll
    for (int i = 0; i < 6; ++i) {
        float m = acc[i][0];
#pragma unroll
        for (int j = 1; j < 6; ++j) m = fmaxf(m, acc[i][j]);
        for (int d = 1; d < 16; d <<= 1) m = fmaxf(m, __shfl_xor(m, d));
        float s = 0.0f;
#pragma unroll
        for (int j = 0; j < 6; ++j) {
            acc[i][j] = __expf(acc[i][j] - m);
            s += acc[i][j];
        }
        for (int d = 1; d < 16; d <<= 1) s += __shfl_xor(s, d);
        float inv = 1.0f / s;
#pragma unroll
        for (int j = 0; j < 6; ++j) acc[i][j] *= inv;
    }

    __syncthreads();
#pragma unroll
    for (int i = 0; i < 6; ++i)
#pragma unroll
        for (int j = 0; j < 6; ++j) R1[(h0 + i) * 101 + g0 + j] = acc[i][j];
    for (int f = t; f < 96 * 24; f += 256) {
        int r = f / 24, w4 = (f % 24) * 4;
        *(float4*)(R2 + r * 101 + w4) = *(const float4*)(v + base + r * 96 + w4);
    }
    __syncthreads();

    int w0 = tx * 6;
    float outv[6][6];
#pragma unroll
    for (int i = 0; i < 6; ++i)
#pragma unroll
        for (int j = 0; j < 6; ++j) outv[i][j] = 0.0f;

    for (int g4 = 0; g4 < 24; ++g4) {
        float4 av[6];
#pragma unroll
        for (int i = 0; i < 6; ++i) av[i] = *(const float4*)(R1 + (h0 + i) * 101 + g4 * 4);
#pragma unroll
        for (int gg = 0; gg < 4; ++gg) {
            int g = g4 * 4 + gg;
            float vr[6];
#pragma unroll
            for (int j = 0; j < 6; ++j) vr[j] = R2[g * 101 + w0 + j];
#pragma unroll
            for (int i = 0; i < 6; ++i) {
                float a = (gg == 0) ? av[i].x : (gg == 1) ? av[i].y : (gg == 2) ? av[i].z : av[i].w;
#pragma unroll
                for (int j = 0; j < 6; ++j) outv[i][j] = fmaf(a, vr[j], outv[i][j]);
            }
        }
    }

#pragma unroll
    for (int i = 0; i < 6; ++i) {
        float* op = fused + base + (size_t)(h0 + i) * 96 + w0;
#pragma unroll
        for (int j = 0; j < 6; ++j) op[j] = outv[i][j];
    }
}

// ---------------------------------------------------------------------------
// Final projection: out[b][o][n] = sum_c proj_w[o][c]*fused[b][c][n] + pb[o]
// ---------------------------------------------------------------------------
__global__ __launch_bounds__(256) void proj_kernel(
    const float* __restrict__ fused, const float* __restrict__ pw,
    const float* __restrict__ pb, float* __restrict__ out)
{
    __shared__ float As[16 * 68];
    __shared__ float Bs[16 * 128];

    int t  = threadIdx.x;
    int n0 = blockIdx.x * 128;
    int b  = blockIdx.y;
    const float* B = fused + (size_t)b * PERB;
    int tx = t & 15, ty = t >> 4;

    float acc[4][8];
#pragma unroll
    for (int i = 0; i < 4; ++i)
#pragma unroll
        for (int j = 0; j < 8; ++j) acc[i][j] = 0.0f;

    for (int k0 = 0; k0 < 256; k0 += 16) {
        {
            int m = t >> 2, c4 = (t & 3) * 4;
            float4 av = *(const float4*)(pw + (size_t)m * 256 + k0 + c4);
            As[(c4 + 0) * 68 + m] = av.x;
            As[(c4 + 1) * 68 + m] = av.y;
            As[(c4 + 2) * 68 + m] = av.z;
            As[(c4 + 3) * 68 + m] = av.w;
        }
#pragma unroll
        for (int l = 0; l < 2; ++l) {
            int f = t + l * 256;
            int c = f >> 5, n4 = (f & 31) * 4;
            *(float4*)(Bs + c * 128 + n4) =
                *(const float4*)(B + (size_t)(k0 + c) * NPOS + n0 + n4);
        }
        __syncthreads();
#pragma unroll
        for (int kk = 0; kk < 16; ++kk) {
            float a[4], bb[8];
            *(float4*)(&a[0])  = *(const float4*)(As + kk * 68 + ty * 4);
            *(float4*)(&bb[0]) = *(const float4*)(Bs + kk * 128 + tx * 8);
            *(float4*)(&bb[4]) = *(const float4*)(Bs + kk * 128 + tx * 8 + 4);
#pragma unroll
            for (int i = 0; i < 4; ++i)
#pragma unroll
                for (int j = 0; j < 8; ++j)
                    acc[i][j] = fmaf(a[i], bb[j], acc[i][j]);
        }
        __syncthreads();
    }

    int n = n0 + tx * 8;
#pragma unroll
    for (int i = 0; i < 4; ++i) {
        int o = ty * 4 + i;
        float bias = pb[o];
        float vals[8];
#pragma unroll
        for (int j = 0; j < 8; ++j) vals[j] = acc[i][j] + bias;
        float* op = out + ((size_t)b * 64 + o) * NPOS + n;
        *(float4*)(op)     = *(float4*)(&vals[0]);
        *(float4*)(op + 4) = *(float4*)(&vals[4]);
    }
}

// ---------------------------------------------------------------------------
extern "C" void kernel_launch(void* const* d_in, const int* in_sizes, int n_in,
                              void* d_out, int out_size, void* d_ws, size_t ws_size,
                              hipStream_t stream)
{
    const float* x1   = (const float*)d_in[0];
    const float* x2   = (const float*)d_in[1];
    const float* wvis = (const float*)d_in[2];
    const float* wir  = (const float*)d_in[3];
    const float* qw   = (const float*)d_in[4];
    const float* qb   = (const float*)d_in[5];
    const float* kw   = (const float*)d_in[6];
    const float* kb   = (const float*)d_in[7];
    const float* vw   = (const float*)d_in[8];
    const float* vb   = (const float*)d_in[9];
    const float* pw   = (const float*)d_in[10];
    const float* pb   = (const float*)d_in[11];
    float* out = (float*)d_out;

    float* ws = (float*)d_ws;
    size_t F = ws_size / 4;
    size_t fixed = 350000;   // T table (24576 f32) + weights (1.18M u16)
    size_t avail = (F > fixed) ? (F - fixed) : 0;
    int G = (int)(avail / (4 * PERB));
    if (G < 1) G = 1;
    if (G > 8) G = 8;

    float* ttab  = ws;                       // 24576 floats
    float* qbuf  = ws + 24576;
    float* kbuf  = qbuf + (size_t)G * PERB;
    float* vbuf  = kbuf + (size_t)G * PERB;
    float* fbuf  = vbuf + (size_t)G * PERB;
    u16*   whiP  = (u16*)(fbuf + (size_t)G * PERB);
    u16*   wloP  = whiP + 589824;

    tt_kernel<<<dim3(96), 256, 0, stream>>>(ttab);
    wsplit<<<dim3(144), 256, 0, stream>>>(qw, kw, vw, whiP, wloP);

    for (int b0 = 0; b0 < 16; b0 += G) {
        int g = (16 - b0 < G) ? (16 - b0) : G;
        for (int s = 0; s < 3; ++s) {
            const float* sq  = (s == 0) ? (x1 + (size_t)b0 * PERB) : fbuf;
            const float* skv = (s == 0) ? (x2 + (size_t)b0 * PERB) : fbuf;
            gemm_qkv_mfma<<<dim3(6, 72, g), 256, 0, stream>>>(
                whiP + (size_t)s * 196608, wloP + (size_t)s * 196608,
                sq, skv,
                qb + (size_t)s * 256, kb + (size_t)s * 256, vb + (size_t)s * 256,
                wvis + (size_t)b0 * NPOS, wir + (size_t)b0 * NPOS,
                ttab, qbuf, kbuf, vbuf);
            attn_kernel<<<dim3(256 * g), 256, 0, stream>>>(qbuf, kbuf, vbuf, fbuf);
        }
        proj_kernel<<<dim3(72, g), 256, 0, stream>>>(
            fbuf, pw, pb, out + (size_t)b0 * 64 * NPOS);
    }
}

// Round 14
// 1913.710 us; speedup vs baseline: 1.1309x; 1.0066x over previous
//
#include <hip/hip_runtime.h>
#include <hip/hip_bf16.h>
#include <math.h>

// Shapes: B=16, C=256, H=W=96, S=3, OUT_C=64
#define NPOS 9216
#define PERB 2359296ull        // 256*9216 elements (one [C][H*W] plane-set)

typedef unsigned short u16;
typedef __attribute__((ext_vector_type(8))) short short8;  // bf16x8 MFMA frag
typedef __attribute__((ext_vector_type(4))) float f32x4;   // MFMA acc

__device__ inline u16 bfhi(float x) {
    unsigned int b = __float_as_uint(x);
    return (u16)((b + 0x7FFFu + ((b >> 16) & 1u)) >> 16);   // RNE f32->bf16
}
__device__ inline float bf2f(u16 u) { return __uint_as_float(((unsigned int)u) << 16); }

// async global->LDS, 16B per lane (dest = uniform base + lane*16)
typedef const __attribute__((address_space(1))) void* gvp;
typedef __attribute__((address_space(3))) void* lvp;
__device__ __forceinline__ void glds16(const void* g, void* l) {
    __builtin_amdgcn_global_load_lds((gvp)g, (lvp)l, 16, 0, 0);
}

// ---------------------------------------------------------------------------
// Separable positional-encoding table: T[c][p], c=4j+r.
// pe[c][h*96+w] == T[c][w] + T[c][h];  r0: sin(p/95*f), r1: cos, r2/3: 0.
// ---------------------------------------------------------------------------
__global__ __launch_bounds__(256) void tt_kernel(float* __restrict__ T)
{
    int idx = blockIdx.x * 256 + threadIdx.x;   // 0..24575 (256c x 96p)
    int c = idx / 96, p = idx - (idx / 96) * 96;
    int j = c >> 2, r = c & 3;
    float f = expf(-(float)(2 * j) * 0.07195578415f);  // ln(10000)/128
    float x = (float)p * (1.0f / 95.0f) * f;
    T[idx] = (r == 0) ? sinf(x) : (r == 1) ? cosf(x) : 0.0f;
}

// ---------------------------------------------------------------------------
// Weight split: W[s][mat][256][256] f32 -> blocked bf16 hi/lo, XOR-swizzled.
// layout: [s][mat*2+mb][kb][128 rows][4 slots][8] with slot ^= (row>>1)&3
// ---------------------------------------------------------------------------
__global__ __launch_bounds__(256) void wsplit(
    const float* __restrict__ qw, const float* __restrict__ kw,
    const float* __restrict__ vw, u16* __restrict__ whi, u16* __restrict__ wlo)
{
    int bid = blockIdx.x;
    int s = bid / 48, rem = bid % 48;
    int mat = rem / 16, rem2 = rem % 16;
    int mb = rem2 / 8, kb = rem2 % 8;
    const float* W = ((mat == 0) ? qw : (mat == 1) ? kw : vw) + (size_t)s * 65536;
    int t = threadIdx.x;
    int m = t >> 1, kh = (t & 1) * 16;
    const float* src = W + (size_t)(mb * 128 + m) * 256 + kb * 32 + kh;
    int s0 = kh >> 3;                  // 0 or 2
    int sw = (m >> 1) & 3;
    size_t ob = (size_t)s * 196608 + (size_t)((mat * 2 + mb) * 8 + kb) * 4096
              + (size_t)m * 32;
    u16 hv[16], lv[16];
#pragma unroll
    for (int j = 0; j < 16; ++j) {
        float x = src[j];
        u16 h = bfhi(x);
        hv[j] = h;
        lv[j] = bfhi(x - bf2f(h));
    }
    *(uint4*)(whi + ob + ((s0 ^ sw) * 8))       = *(uint4*)hv;
    *(uint4*)(whi + ob + (((s0 + 1) ^ sw) * 8)) = *(uint4*)(hv + 8);
    *(uint4*)(wlo + ob + ((s0 ^ sw) * 8))       = *(uint4*)lv;
    *(uint4*)(wlo + ob + (((s0 + 1) ^ sw) * 8)) = *(uint4*)(lv + 8);
}

// ---------------------------------------------------------------------------
// MFMA QKV GEMM, split-bf16 — m97 structure; A (weights) via glds16 from the
// blocked/swizzled u16 layout; B staged directly from the f32 source plane
// with inline hi/lo split + transpose.  Barrier2 is RAW (lgkmcnt-only) so the
// B prefetch for step k+1 stays in flight across it (T4: never drain vmcnt 0).
// ---------------------------------------------------------------------------
__global__ __launch_bounds__(256, 3) void gemm_qkv_mfma(
    const u16* __restrict__ whi, const u16* __restrict__ wlo,
    const float* __restrict__ srcq, const float* __restrict__ srckv,
    const float* __restrict__ qb, const float* __restrict__ kbias,
    const float* __restrict__ vb, const float* __restrict__ wvis,
    const float* __restrict__ wir, const float* __restrict__ Ttab,
    float* __restrict__ qo, float* __restrict__ ko, float* __restrict__ vo)
{
    __shared__ u16 AH[4096], AL[4096], BH[4096], BL[4096];   // 32KB staging
    __shared__ float SB[4][16][68];                          // 17KB epilogue

    int t = threadIdx.x;
    // bijective XCD-chunk swizzle: 432 = 54*8; consecutive roles share an XCD
    int d = blockIdx.x + 6 * blockIdx.y;           // 0..431 (dispatch order)
    int role = (d & 7) * 54 + (d >> 3);
    int mat = role / 144, rem = role - mat * 144;
    int bn = rem >> 1, mtile = rem & 1;            // mtile pair adjacent roles
    int b = blockIdx.z;

    const float* gB = ((mat == 0) ? srcq : srckv) + (size_t)b * PERB + bn * 128;
    const u16* gAh = whi + (size_t)(mat * 2 + mtile) * 32768;
    const u16* gAl = wlo + (size_t)(mat * 2 + mtile) * 32768;
    int wv = t >> 6;
    int wm = t >> 7, wn = (t >> 6) & 1;
    int rr = t & 15, gq = (t >> 4) & 3;

    // f-independent swizzled frag base offsets (u16 units); frag f adds f*512
    int sxor = (gq ^ ((rr >> 1) & 3)) * 8;
    int offA0 = (wm * 64 + rr) * 32 + sxor;
    int offB0 = (wn * 64 + rr) * 32 + sxor;

    // B-staging mapping: thread covers (n = t&127, k = (t>>7)*16 + j)
    int bn_ = t & 127, bkh = t >> 7;
    int key = (bn_ >> 1) & 3;
    int wr0 = bn_ * 32 + (((bkh * 2)     ^ key) * 8);
    int wr1 = bn_ * 32 + (((bkh * 2 + 1) ^ key) * 8);
    const float* bp = gB + (size_t)(bkh * 16) * NPOS + bn_;

    f32x4 acc[4][4];
#pragma unroll
    for (int i = 0; i < 4; ++i)
#pragma unroll
        for (int j = 0; j < 4; ++j) acc[i][j] = (f32x4){0.f, 0.f, 0.f, 0.f};

    // prologue: load B tile 0 into regs (coalesced dword per lane)
    float xv[16];
#pragma unroll
    for (int j = 0; j < 16; ++j) xv[j] = bp[(size_t)j * NPOS];

    for (int kq = 0; kq < 8; ++kq) {
        {   // stage A tile via glds16 (pre-swizzled blocked layout)
            const u16* sah = gAh + kq * 4096 + t * 8;
            const u16* sal = gAl + kq * 4096 + t * 8;
            glds16(sah,        &AH[t * 8]);
            glds16(sah + 2048, &AH[t * 8 + 2048]);
            glds16(sal,        &AL[t * 8]);
            glds16(sal + 2048, &AL[t * 8 + 2048]);
        }
        {   // convert current B regs -> swizzled LDS (hi/lo)
            u16 hv[16], lv[16];
#pragma unroll
            for (int j = 0; j < 16; ++j) {
                float x = xv[j];
                u16 h = bfhi(x);
                hv[j] = h;
                lv[j] = bfhi(x - bf2f(h));
            }
            *(uint4*)(&BH[wr0]) = *(uint4*)hv;
            *(uint4*)(&BH[wr1]) = *(uint4*)(hv + 8);
            *(uint4*)(&BL[wr0]) = *(uint4*)lv;
            *(uint4*)(&BL[wr1]) = *(uint4*)(lv + 8);
        }
        __syncthreads();    // must drain A glds16 (vmcnt) + B ds_writes (lgkm)

        // issue next-tile B loads; they stay in flight across the RAW barrier
        if (kq < 7) {
#pragma unroll
            for (int j = 0; j < 16; ++j)
                xv[j] = bp[(size_t)((kq + 1) * 32 + j) * NPOS];
        }

        short8 bh[4], bl[4];
#pragma unroll
        for (int r = 0; r < 4; ++r) {
            bh[r] = *(const short8*)(&BH[offB0 + r * 512]);
            bl[r] = *(const short8*)(&BL[offB0 + r * 512]);
        }
#pragma unroll
        for (int f = 0; f < 4; ++f) {
            short8 ah = *(const short8*)(&AH[offA0 + f * 512]);
            short8 al = *(const short8*)(&AL[offA0 + f * 512]);
#pragma unroll
            for (int r = 0; r < 4; ++r) {
                acc[f][r] = __builtin_amdgcn_mfma_f32_16x16x32_bf16(ah, bh[r], acc[f][r], 0, 0, 0);
                acc[f][r] = __builtin_amdgcn_mfma_f32_16x16x32_bf16(ah, bl[r], acc[f][r], 0, 0, 0);
                acc[f][r] = __builtin_amdgcn_mfma_f32_16x16x32_bf16(al, bh[r], acc[f][r], 0, 0, 0);
            }
        }
        // RAW barrier: protect LDS reuse (lgkm only); B loads stay in flight.
        asm volatile("s_waitcnt lgkmcnt(0)" ::: "memory");
        __builtin_amdgcn_s_barrier();
        __builtin_amdgcn_sched_barrier(0);
    }

    // ---- vectorized epilogue: per-wave LDS bounce, float4 stores ----
    const float* wmap = ((mat == 0) ? wvis : wir) + (size_t)b * NPOS;
    const float* bias = (mat == 0) ? qb : (mat == 1) ? kbias : vb;
    float* outp = ((mat == 0) ? qo : (mat == 1) ? ko : vo) + (size_t)b * PERB;
    bool addpe = (mat != 2);

    int lane = t & 63;
    int lrow = lane >> 2;           // 0..15 (o-row within 16-slab)
    int lq   = lane & 3;            // col quarter
    int base_n = bn * 128 + wn * 64;

#pragma unroll
    for (int f = 0; f < 4; ++f) {
        // scatter this wave's 16x64 acc slab into SB (2-way banks = free)
#pragma unroll
        for (int r = 0; r < 4; ++r)
#pragma unroll
            for (int ri = 0; ri < 4; ++ri)
                SB[wv][gq * 4 + ri][r * 16 + rr] = acc[f][r][ri];
        // gather rows: lane owns (o = base_o + lrow, n = base_n + lq*16 + 4q)
        int o = mtile * 128 + wm * 64 + f * 16 + lrow;
        float bo = bias[o];
        const float* tro = Ttab + o * 96;
        float* orow = outp + (size_t)o * NPOS;
#pragma unroll
        for (int qd = 0; qd < 4; ++qd) {
            int c0 = lq * 16 + qd * 4;
            int n = base_n + c0;
            float4 v4 = *(float4*)&SB[wv][lrow][c0];
            float4 s4 = *(const float4*)&wmap[n];
            float4 o4;
            if (addpe) {
                int hh = n / 96, ww = n - hh * 96;   // quad never crosses a row
                float4 pw4 = *(const float4*)&tro[ww];
                float ph = tro[hh];
                o4.x = v4.x * s4.x + bo + pw4.x + ph;
                o4.y = v4.y * s4.y + bo + pw4.y + ph;
                o4.z = v4.z * s4.z + bo + pw4.z + ph;
                o4.w = v4.w * s4.w + bo + pw4.w + ph;
            } else {
                o4.x = v4.x * s4.x + bo;
                o4.y = v4.y * s4.y + bo;
                o4.z = v4.z * s4.z + bo;
                o4.w = v4.w * s4.w + bo;
            }
            *(float4*)&orow[n] = o4;
        }
        // next f reuses SB; wave-internal LDS ordering handles the hazard
    }
}

// ---------------------------------------------------------------------------
// Attention per (b,c): pitch-102 LDS (<=2-way banks, 8B-aligned rows).
// R1 = q then attn; R2 = k then v.  PV reads via float2 (halved LDS issues).
// ---------------------------------------------------------------------------
__global__ __launch_bounds__(256) void attn_kernel(
    const float* __restrict__ q, const float* __restrict__ k,
    const float* __restrict__ v, float* __restrict__ fused)
{
    __shared__ float R1[96 * 102];  // q, later attn
    __shared__ float R2[96 * 102];  // k, later v

    int t  = threadIdx.x;
    int bc = blockIdx.x;
    const size_t base = (size_t)bc * NPOS;

    for (int f = t; f < 96 * 24; f += 256) {
        int r = f / 24, w4 = (f % 24) * 4;
        *(float4*)(R1 + r * 102 + w4) = *(const float4*)(q + base + r * 96 + w4);
        *(float4*)(R2 + r * 102 + w4) = *(const float4*)(k + base + r * 96 + w4);
    }
    __syncthreads();

    int tx = t & 15, ty = t >> 4;
    int h0 = ty * 6, g0 = tx * 6;

    float acc[6][6];
#pragma unroll
    for (int i = 0; i < 6; ++i)
#pragma unroll
        for (int j = 0; j < 6; ++j) acc[i][j] = 0.0f;

    for (int w4 = 0; w4 < 24; ++w4) {
        float4 qv[6], kv[6];
#pragma unroll
        for (int i = 0; i < 6; ++i) qv[i] = *(const float4*)(R1 + (h0 + i) * 102 + w4 * 4);
#pragma unroll
        for (int j = 0; j < 6; ++j) kv[j] = *(const float4*)(R2 + (g0 + j) * 102 + w4 * 4);
#pragma unroll
        for (int i = 0; i < 6; ++i)
#pragma unroll
            for (int j = 0; j < 6; ++j) {
                acc[i][j] = fmaf(qv[i].x, kv[j].x, acc[i][j]);
                acc[i][j] = fmaf(qv[i].y, kv[j].y, acc[i][j]);
                acc[i][j] = fmaf(qv[i].z, kv[j].z, acc[i][j]);
                acc[i][j] = fmaf(qv[i].w, kv[j].w, acc[i][j]);
            }
    }

#pragma unroll
    for (int i = 0; i < 6; ++i) {
        float m = acc[i][0];
#pragma unroll
        for (int j = 1; j < 6; ++j) m = fmaxf(m, acc[i][j]);
        for (int d = 1; d < 16; d <<= 1) m = fmaxf(m, __shfl_xor(m, d));
        float s = 0.0f;
#pragma unroll
        for (int j = 0; j < 6; ++j) {
            acc[i][j] = __expf(acc[i][j] - m);
            s += acc[i][j];
        }
        for (int d = 1; d < 16; d <<= 1) s += __shfl_xor(s, d);
        float inv = 1.0f / s;
#pragma unroll
        for (int j = 0; j < 6; ++j) acc[i][j] *= inv;
    }

    __syncthreads();
#pragma unroll
    for (int i = 0; i < 6; ++i)
#pragma unroll
        for (int j = 0; j < 6; ++j) R1[(h0 + i) * 102 + g0 + j] = acc[i][j];
    for (int f = t; f < 96 * 24; f += 256) {
        int r = f / 24, w4 = (f % 24) * 4;
        *(float4*)(R2 + r * 102 + w4) = *(const float4*)(v + base + r * 96 + w4);
    }
    __syncthreads();

    int w0 = tx * 6;
    float outv[6][6];
#pragma unroll
    for (int i = 0; i < 6; ++i)
#pragma unroll
        for (int j = 0; j < 6; ++j) outv[i][j] = 0.0f;

    for (int g4 = 0; g4 < 24; ++g4) {
        float4 av[6];
#pragma unroll
        for (int i = 0; i < 6; ++i) av[i] = *(const float4*)(R1 + (h0 + i) * 102 + g4 * 4);
#pragma unroll
        for (int gg = 0; gg < 4; ++gg) {
            int g = g4 * 4 + gg;
            const float* vrow = R2 + g * 102 + w0;
            float2 v0 = *(const float2*)(vrow);
            float2 v1 = *(const float2*)(vrow + 2);
            float2 v2 = *(const float2*)(vrow + 4);
            float vr[6] = {v0.x, v0.y, v1.x, v1.y, v2.x, v2.y};
#pragma unroll
            for (int i = 0; i < 6; ++i) {
                float a = (gg == 0) ? av[i].x : (gg == 1) ? av[i].y : (gg == 2) ? av[i].z : av[i].w;
#pragma unroll
                for (int j = 0; j < 6; ++j) outv[i][j] = fmaf(a, vr[j], outv[i][j]);
            }
        }
    }

#pragma unroll
    for (int i = 0; i < 6; ++i) {
        float* op = fused + base + (size_t)(h0 + i) * 96 + w0;
#pragma unroll
        for (int j = 0; j < 6; ++j) op[j] = outv[i][j];
    }
}

// ---------------------------------------------------------------------------
// Final projection: out[b][o][n] = sum_c proj_w[o][c]*fused[b][c][n] + pb[o]
// ---------------------------------------------------------------------------
__global__ __launch_bounds__(256) void proj_kernel(
    const float* __restrict__ fused, const float* __restrict__ pw,
    const float* __restrict__ pb, float* __restrict__ out)
{
    __shared__ float As[16 * 68];
    __shared__ float Bs[16 * 128];

    int t  = threadIdx.x;
    int n0 = blockIdx.x * 128;
    int b  = blockIdx.y;
    const float* B = fused + (size_t)b * PERB;
    int tx = t & 15, ty = t >> 4;

    float acc[4][8];
#pragma unroll
    for (int i = 0; i < 4; ++i)
#pragma unroll
        for (int j = 0; j < 8; ++j) acc[i][j] = 0.0f;

    for (int k0 = 0; k0 < 256; k0 += 16) {
        {
            int m = t >> 2, c4 = (t & 3) * 4;
            float4 av = *(const float4*)(pw + (size_t)m * 256 + k0 + c4);
            As[(c4 + 0) * 68 + m] = av.x;
            As[(c4 + 1) * 68 + m] = av.y;
            As[(c4 + 2) * 68 + m] = av.z;
            As[(c4 + 3) * 68 + m] = av.w;
        }
#pragma unroll
        for (int l = 0; l < 2; ++l) {
            int f = t + l * 256;
            int c = f >> 5, n4 = (f & 31) * 4;
            *(float4*)(Bs + c * 128 + n4) =
                *(const float4*)(B + (size_t)(k0 + c) * NPOS + n0 + n4);
        }
        __syncthreads();
#pragma unroll
        for (int kk = 0; kk < 16; ++kk) {
            float a[4], bb[8];
            *(float4*)(&a[0])  = *(const float4*)(As + kk * 68 + ty * 4);
            *(float4*)(&bb[0]) = *(const float4*)(Bs + kk * 128 + tx * 8);
            *(float4*)(&bb[4]) = *(const float4*)(Bs + kk * 128 + tx * 8 + 4);
#pragma unroll
            for (int i = 0; i < 4; ++i)
#pragma unroll
                for (int j = 0; j < 8; ++j)
                    acc[i][j] = fmaf(a[i], bb[j], acc[i][j]);
        }
        __syncthreads();
    }

    int n = n0 + tx * 8;
#pragma unroll
    for (int i = 0; i < 4; ++i) {
        int o = ty * 4 + i;
        float bias = pb[o];
        float vals[8];
#pragma unroll
        for (int j = 0; j < 8; ++j) vals[j] = acc[i][j] + bias;
        float* op = out + ((size_t)b * 64 + o) * NPOS + n;
        *(float4*)(op)     = *(float4*)(&vals[0]);
        *(float4*)(op + 4) = *(float4*)(&vals[4]);
    }
}

// ---------------------------------------------------------------------------
extern "C" void kernel_launch(void* const* d_in, const int* in_sizes, int n_in,
                              void* d_out, int out_size, void* d_ws, size_t ws_size,
                              hipStream_t stream)
{
    const float* x1   = (const float*)d_in[0];
    const float* x2   = (const float*)d_in[1];
    const float* wvis = (const float*)d_in[2];
    const float* wir  = (const float*)d_in[3];
    const float* qw   = (const float*)d_in[4];
    const float* qb   = (const float*)d_in[5];
    const float* kw   = (const float*)d_in[6];
    const float* kb   = (const float*)d_in[7];
    const float* vw   = (const float*)d_in[8];
    const float* vb   = (const float*)d_in[9];
    const float* pw   = (const float*)d_in[10];
    const float* pb   = (const float*)d_in[11];
    float* out = (float*)d_out;

    float* ws = (float*)d_ws;
    size_t F = ws_size / 4;
    size_t fixed = 350000;   // T table (24576 f32) + weights (1.18M u16)
    size_t avail = (F > fixed) ? (F - fixed) : 0;
    int G = (int)(avail / (4 * PERB));
    if (G < 1) G = 1;
    if (G > 8) G = 8;

    float* ttab  = ws;                       // 24576 floats
    float* qbuf  = ws + 24576;
    float* kbuf  = qbuf + (size_t)G * PERB;
    float* vbuf  = kbuf + (size_t)G * PERB;
    float* fbuf  = vbuf + (size_t)G * PERB;
    u16*   whiP  = (u16*)(fbuf + (size_t)G * PERB);
    u16*   wloP  = whiP + 589824;

    tt_kernel<<<dim3(96), 256, 0, stream>>>(ttab);
    wsplit<<<dim3(144), 256, 0, stream>>>(qw, kw, vw, whiP, wloP);

    for (int b0 = 0; b0 < 16; b0 += G) {
        int g = (16 - b0 < G) ? (16 - b0) : G;
        for (int s = 0; s < 3; ++s) {
            const float* sq  = (s == 0) ? (x1 + (size_t)b0 * PERB) : fbuf;
            const float* skv = (s == 0) ? (x2 + (size_t)b0 * PERB) : fbuf;
            gemm_qkv_mfma<<<dim3(6, 72, g), 256, 0, stream>>>(
                whiP + (size_t)s * 196608, wloP + (size_t)s * 196608,
                sq, skv,
                qb + (size_t)s * 256, kb + (size_t)s * 256, vb + (size_t)s * 256,
                wvis + (size_t)b0 * NPOS, wir + (size_t)b0 * NPOS,
                ttab, qbuf, kbuf, vbuf);
            attn_kernel<<<dim3(256 * g), 256, 0, stream>>>(qbuf, kbuf, vbuf, fbuf);
        }
        proj_kernel<<<dim3(72, g), 256, 0, stream>>>(
            fbuf, pw, pb, out + (size_t)b0 * 64 * NPOS);
    }
}

// Round 15
// 1902.782 us; speedup vs baseline: 1.1374x; 1.0057x over previous
//
#include <hip/hip_runtime.h>
#include <hip/hip_bf16.h>
#include <math.h>

// Shapes: B=16, C=256, H=W=96, S=3, OUT_C=64
#define NPOS 9216
#define PERB 2359296ull        // 256*9216 elements (one [C][H*W] plane-set)

typedef unsigned short u16;
typedef __attribute__((ext_vector_type(8))) short short8;  // bf16x8 MFMA frag
typedef __attribute__((ext_vector_type(4))) float f32x4;   // MFMA acc

__device__ inline u16 bfhi(float x) {
    unsigned int b = __float_as_uint(x);
    return (u16)((b + 0x7FFFu + ((b >> 16) & 1u)) >> 16);   // RNE f32->bf16
}
__device__ inline float bf2f(u16 u) { return __uint_as_float(((unsigned int)u) << 16); }

// async global->LDS, 16B per lane (dest = uniform base + lane*16)
typedef const __attribute__((address_space(1))) void* gvp;
typedef __attribute__((address_space(3))) void* lvp;
__device__ __forceinline__ void glds16(const void* g, void* l) {
    __builtin_amdgcn_global_load_lds((gvp)g, (lvp)l, 16, 0, 0);
}

// ---------------------------------------------------------------------------
// Separable positional-encoding table: T[c][p], c=4j+r.
// pe[c][h*96+w] == T[c][w] + T[c][h];  r0: sin(p/95*f), r1: cos, r2/3: 0.
// ---------------------------------------------------------------------------
__global__ __launch_bounds__(256) void tt_kernel(float* __restrict__ T)
{
    int idx = blockIdx.x * 256 + threadIdx.x;   // 0..24575 (256c x 96p)
    int c = idx / 96, p = idx - (idx / 96) * 96;
    int j = c >> 2, r = c & 3;
    float f = expf(-(float)(2 * j) * 0.07195578415f);  // ln(10000)/128
    float x = (float)p * (1.0f / 95.0f) * f;
    T[idx] = (r == 0) ? sinf(x) : (r == 1) ? cosf(x) : 0.0f;
}

// ---------------------------------------------------------------------------
// Weight split: W[s][mat][256][256] f32 -> blocked bf16 hi/lo, XOR-swizzled.
// layout: [s][mat*2+mb][kb][128 rows][4 slots][8] with slot ^= (row>>1)&3
// ---------------------------------------------------------------------------
__global__ __launch_bounds__(256) void wsplit(
    const float* __restrict__ qw, const float* __restrict__ kw,
    const float* __restrict__ vw, u16* __restrict__ whi, u16* __restrict__ wlo)
{
    int bid = blockIdx.x;
    int s = bid / 48, rem = bid % 48;
    int mat = rem / 16, rem2 = rem % 16;
    int mb = rem2 / 8, kb = rem2 % 8;
    const float* W = ((mat == 0) ? qw : (mat == 1) ? kw : vw) + (size_t)s * 65536;
    int t = threadIdx.x;
    int m = t >> 1, kh = (t & 1) * 16;
    const float* src = W + (size_t)(mb * 128 + m) * 256 + kb * 32 + kh;
    int s0 = kh >> 3;                  // 0 or 2
    int sw = (m >> 1) & 3;
    size_t ob = (size_t)s * 196608 + (size_t)((mat * 2 + mb) * 8 + kb) * 4096
              + (size_t)m * 32;
    u16 hv[16], lv[16];
#pragma unroll
    for (int j = 0; j < 16; ++j) {
        float x = src[j];
        u16 h = bfhi(x);
        hv[j] = h;
        lv[j] = bfhi(x - bf2f(h));
    }
    *(uint4*)(whi + ob + ((s0 ^ sw) * 8))       = *(uint4*)hv;
    *(uint4*)(whi + ob + (((s0 + 1) ^ sw) * 8)) = *(uint4*)(hv + 8);
    *(uint4*)(wlo + ob + ((s0 ^ sw) * 8))       = *(uint4*)lv;
    *(uint4*)(wlo + ob + (((s0 + 1) ^ sw) * 8)) = *(uint4*)(lv + 8);
}

// ---------------------------------------------------------------------------
// MFMA QKV GEMM, split-bf16 — FAT-M: 512-thread block computes one mat's full
// M=256 x N=128 tile (8 waves, 4m x 2n).  A via glds16 (blocked/swizzled);
// B staged from the f32 source with inline hi/lo split.  3 blocks/CU.
// ---------------------------------------------------------------------------
__global__ __launch_bounds__(512, 4) void gemm_qkv_mfma(
    const u16* __restrict__ whi, const u16* __restrict__ wlo,
    const float* __restrict__ srcq, const float* __restrict__ srckv,
    const float* __restrict__ qb, const float* __restrict__ kbias,
    const float* __restrict__ vb, const float* __restrict__ wvis,
    const float* __restrict__ wir, const float* __restrict__ Ttab,
    float* __restrict__ qo, float* __restrict__ ko, float* __restrict__ vo)
{
    __shared__ char LDSBUF[49152];          // A(32KB) + B(16KB); epilogue SB aliases
    u16* AH = (u16*)LDSBUF;                 // [256][32]  (8192 u16)
    u16* AL = AH + 8192;
    u16* BH = AL + 8192;                    // [128][32]  (4096 u16)
    u16* BL = BH + 4096;

    int t = threadIdx.x;
    // bijective XCD-chunk swizzle: 216 = 27*8
    int d = blockIdx.x + 3 * blockIdx.y;           // 0..215
    int role = (d & 7) * 27 + (d >> 3);
    int mat = role / 72, bn = role % 72;
    int b = blockIdx.z;

    const float* gB = ((mat == 0) ? srcq : srckv) + (size_t)b * PERB + bn * 128;
    const u16* gA0 = whi + (size_t)(mat * 2) * 32768;   // hi tiles mb=0,1
    const u16* gA1 = wlo + (size_t)(mat * 2) * 32768;

    int wv = t >> 6;
    int wm = wv >> 1, wn = wv & 1;                 // 4m x 2n wave grid
    int rr = t & 15, gq = (t >> 4) & 3;

    // f-independent swizzled frag base offsets (u16 units); frag f adds f*512
    int sxor = (gq ^ ((rr >> 1) & 3)) * 8;
    int offA0 = (wm * 64 + rr) * 32 + sxor;        // rows 0..255
    int offB0 = (wn * 64 + rr) * 32 + sxor;        // cols 0..127

    // A staging: thread t covers AH[t*8..] (row=t>>2 in mb=0) and +4096 (mb=1)
    int arow = t >> 2, acol = (t & 3) * 8;
    size_t asrc0 = (size_t)arow * 32 + acol;                 // within tile mb=0
    size_t asrc1 = 32768 + (size_t)arow * 32 + acol;         // tile mb=1

    // B-staging mapping: thread covers (n = t&127, k = (t>>7)*8 + j)
    int bn_ = t & 127, bkh = t >> 7;               // bkh 0..3
    int key = (bn_ >> 1) & 3;
    int wrB = bn_ * 32 + ((bkh ^ key) * 8);
    const float* bp = gB + (size_t)(bkh * 8) * NPOS + bn_;

    f32x4 acc[4][4];
#pragma unroll
    for (int i = 0; i < 4; ++i)
#pragma unroll
        for (int j = 0; j < 4; ++j) acc[i][j] = (f32x4){0.f, 0.f, 0.f, 0.f};

    // prologue: load B tile 0 into regs (coalesced dword per lane)
    float xv[8];
#pragma unroll
    for (int j = 0; j < 8; ++j) xv[j] = bp[(size_t)j * NPOS];

    for (int kq = 0; kq < 8; ++kq) {
        {   // stage A tile via glds16 (pre-swizzled blocked layout)
            glds16(gA0 + kq * 4096 + asrc0, &AH[t * 8]);
            glds16(gA0 + kq * 4096 + asrc1, &AH[t * 8 + 4096]);
            glds16(gA1 + kq * 4096 + asrc0, &AL[t * 8]);
            glds16(gA1 + kq * 4096 + asrc1, &AL[t * 8 + 4096]);
        }
        {   // convert current B regs -> swizzled LDS (hi/lo)
            u16 hv[8], lv[8];
#pragma unroll
            for (int j = 0; j < 8; ++j) {
                float x = xv[j];
                u16 h = bfhi(x);
                hv[j] = h;
                lv[j] = bfhi(x - bf2f(h));
            }
            *(uint4*)(&BH[wrB]) = *(uint4*)hv;
            *(uint4*)(&BL[wrB]) = *(uint4*)lv;
        }
        __syncthreads();    // drains A glds16 (vmcnt) + B ds_writes (lgkm)

        // issue next-tile B loads; they stay in flight across the RAW barrier
        if (kq < 7) {
#pragma unroll
            for (int j = 0; j < 8; ++j)
                xv[j] = bp[(size_t)((kq + 1) * 32 + j) * NPOS];
        }

        short8 bh[4], bl[4];
#pragma unroll
        for (int r = 0; r < 4; ++r) {
            bh[r] = *(const short8*)(&BH[offB0 + r * 512]);
            bl[r] = *(const short8*)(&BL[offB0 + r * 512]);
        }
#pragma unroll
        for (int f = 0; f < 4; ++f) {
            short8 ah = *(const short8*)(&AH[offA0 + f * 512]);
            short8 al = *(const short8*)(&AL[offA0 + f * 512]);
#pragma unroll
            for (int r = 0; r < 4; ++r) {
                acc[f][r] = __builtin_amdgcn_mfma_f32_16x16x32_bf16(ah, bh[r], acc[f][r], 0, 0, 0);
                acc[f][r] = __builtin_amdgcn_mfma_f32_16x16x32_bf16(ah, bl[r], acc[f][r], 0, 0, 0);
                acc[f][r] = __builtin_amdgcn_mfma_f32_16x16x32_bf16(al, bh[r], acc[f][r], 0, 0, 0);
            }
        }
        // RAW barrier: protect LDS reuse (lgkm only); B loads stay in flight.
        asm volatile("s_waitcnt lgkmcnt(0)" ::: "memory");
        __builtin_amdgcn_s_barrier();
        __builtin_amdgcn_sched_barrier(0);
    }

    // ---- vectorized epilogue: per-wave LDS bounce (aliased onto staging) ----
    float* SB = (float*)LDSBUF + (size_t)wv * (16 * 68);   // 8 x 4.35KB = 34.8KB
    const float* wmap = ((mat == 0) ? wvis : wir) + (size_t)b * NPOS;
    const float* bias = (mat == 0) ? qb : (mat == 1) ? kbias : vb;
    float* outp = ((mat == 0) ? qo : (mat == 1) ? ko : vo) + (size_t)b * PERB;
    bool addpe = (mat != 2);

    int lane = t & 63;
    int lrow = lane >> 2;           // 0..15 (o-row within 16-slab)
    int lq   = lane & 3;            // col quarter
    int base_n = bn * 128 + wn * 64;

#pragma unroll
    for (int f = 0; f < 4; ++f) {
        // scatter this wave's 16x64 acc slab into SB (2-way banks = free)
#pragma unroll
        for (int r = 0; r < 4; ++r)
#pragma unroll
            for (int ri = 0; ri < 4; ++ri)
                SB[(gq * 4 + ri) * 68 + (r * 16 + rr)] = acc[f][r][ri];
        // gather rows: lane owns (o = wm*64 + f*16 + lrow, n = base_n + lq*16 + 4q)
        int o = wm * 64 + f * 16 + lrow;
        float bo = bias[o];
        const float* tro = Ttab + o * 96;
        float* orow = outp + (size_t)o * NPOS;
#pragma unroll
        for (int qd = 0; qd < 4; ++qd) {
            int c0 = lq * 16 + qd * 4;
            int n = base_n + c0;
            float4 v4 = *(float4*)&SB[lrow * 68 + c0];
            float4 s4 = *(const float4*)&wmap[n];
            float4 o4;
            if (addpe) {
                int hh = n / 96, ww = n - hh * 96;   // quad never crosses a row
                float4 pw4 = *(const float4*)&tro[ww];
                float ph = tro[hh];
                o4.x = v4.x * s4.x + bo + pw4.x + ph;
                o4.y = v4.y * s4.y + bo + pw4.y + ph;
                o4.z = v4.z * s4.z + bo + pw4.z + ph;
                o4.w = v4.w * s4.w + bo + pw4.w + ph;
            } else {
                o4.x = v4.x * s4.x + bo;
                o4.y = v4.y * s4.y + bo;
                o4.z = v4.z * s4.z + bo;
                o4.w = v4.w * s4.w + bo;
            }
            *(float4*)&orow[n] = o4;
        }
        // next f reuses SB; wave-internal LDS ordering handles the hazard
    }
}

// ---------------------------------------------------------------------------
// Attention per (b,c): pitch-102 LDS (<=2-way banks, 8B-aligned rows).
// R1 = q then attn; R2 = k then v.  PV reads via float2.
// ---------------------------------------------------------------------------
__global__ __launch_bounds__(256) void attn_kernel(
    const float* __restrict__ q, const float* __restrict__ k,
    const float* __restrict__ v, float* __restrict__ fused)
{
    __shared__ float R1[96 * 102];  // q, later attn
    __shared__ float R2[96 * 102];  // k, later v

    int t  = threadIdx.x;
    int bc = blockIdx.x;
    const size_t base = (size_t)bc * NPOS;

    for (int f = t; f < 96 * 24; f += 256) {
        int r = f / 24, w4 = (f % 24) * 4;
        *(float4*)(R1 + r * 102 + w4) = *(const float4*)(q + base + r * 96 + w4);
        *(float4*)(R2 + r * 102 + w4) = *(const float4*)(k + base + r * 96 + w4);
    }
    __syncthreads();

    int tx = t & 15, ty = t >> 4;
    int h0 = ty * 6, g0 = tx * 6;

    float acc[6][6];
#pragma unroll
    for (int i = 0; i < 6; ++i)
#pragma unroll
        for (int j = 0; j < 6; ++j) acc[i][j] = 0.0f;

    for (int w4 = 0; w4 < 24; ++w4) {
        float4 qv[6], kv[6];
#pragma unroll
        for (int i = 0; i < 6; ++i) qv[i] = *(const float4*)(R1 + (h0 + i) * 102 + w4 * 4);
#pragma unroll
        for (int j = 0; j < 6; ++j) kv[j] = *(const float4*)(R2 + (g0 + j) * 102 + w4 * 4);
#pragma unroll
        for (int i = 0; i < 6; ++i)
#pragma unroll
            for (int j = 0; j < 6; ++j) {
                acc[i][j] = fmaf(qv[i].x, kv[j].x, acc[i][j]);
                acc[i][j] = fmaf(qv[i].y, kv[j].y, acc[i][j]);
                acc[i][j] = fmaf(qv[i].z, kv[j].z, acc[i][j]);
                acc[i][j] = fmaf(qv[i].w, kv[j].w, acc[i][j]);
            }
    }

#pragma unroll
    for (int i = 0; i < 6; ++i) {
        float m = acc[i][0];
#pragma unroll
        for (int j = 1; j < 6; ++j) m = fmaxf(m, acc[i][j]);
        for (int d = 1; d < 16; d <<= 1) m = fmaxf(m, __shfl_xor(m, d));
        float s = 0.0f;
#pragma unroll
        for (int j = 0; j < 6; ++j) {
            acc[i][j] = __expf(acc[i][j] - m);
            s += acc[i][j];
        }
        for (int d = 1; d < 16; d <<= 1) s += __shfl_xor(s, d);
        float inv = 1.0f / s;
#pragma unroll
        for (int j = 0; j < 6; ++j) acc[i][j] *= inv;
    }

    __syncthreads();
#pragma unroll
    for (int i = 0; i < 6; ++i)
#pragma unroll
        for (int j = 0; j < 6; ++j) R1[(h0 + i) * 102 + g0 + j] = acc[i][j];
    for (int f = t; f < 96 * 24; f += 256) {
        int r = f / 24, w4 = (f % 24) * 4;
        *(float4*)(R2 + r * 102 + w4) = *(const float4*)(v + base + r * 96 + w4);
    }
    __syncthreads();

    int w0 = tx * 6;
    float outv[6][6];
#pragma unroll
    for (int i = 0; i < 6; ++i)
#pragma unroll
        for (int j = 0; j < 6; ++j) outv[i][j] = 0.0f;

    for (int g4 = 0; g4 < 24; ++g4) {
        float4 av[6];
#pragma unroll
        for (int i = 0; i < 6; ++i) av[i] = *(const float4*)(R1 + (h0 + i) * 102 + g4 * 4);
#pragma unroll
        for (int gg = 0; gg < 4; ++gg) {
            int g = g4 * 4 + gg;
            const float* vrow = R2 + g * 102 + w0;
            float2 v0 = *(const float2*)(vrow);
            float2 v1 = *(const float2*)(vrow + 2);
            float2 v2 = *(const float2*)(vrow + 4);
            float vr[6] = {v0.x, v0.y, v1.x, v1.y, v2.x, v2.y};
#pragma unroll
            for (int i = 0; i < 6; ++i) {
                float a = (gg == 0) ? av[i].x : (gg == 1) ? av[i].y : (gg == 2) ? av[i].z : av[i].w;
#pragma unroll
                for (int j = 0; j < 6; ++j) outv[i][j] = fmaf(a, vr[j], outv[i][j]);
            }
        }
    }

#pragma unroll
    for (int i = 0; i < 6; ++i) {
        float* op = fused + base + (size_t)(h0 + i) * 96 + w0;
#pragma unroll
        for (int j = 0; j < 6; ++j) op[j] = outv[i][j];
    }
}

// ---------------------------------------------------------------------------
// Final projection: out[b][o][n] = sum_c proj_w[o][c]*fused[b][c][n] + pb[o]
// ---------------------------------------------------------------------------
__global__ __launch_bounds__(256) void proj_kernel(
    const float* __restrict__ fused, const float* __restrict__ pw,
    const float* __restrict__ pb, float* __restrict__ out)
{
    __shared__ float As[16 * 68];
    __shared__ float Bs[16 * 128];

    int t  = threadIdx.x;
    int n0 = blockIdx.x * 128;
    int b  = blockIdx.y;
    const float* B = fused + (size_t)b * PERB;
    int tx = t & 15, ty = t >> 4;

    float acc[4][8];
#pragma unroll
    for (int i = 0; i < 4; ++i)
#pragma unroll
        for (int j = 0; j < 8; ++j) acc[i][j] = 0.0f;

    for (int k0 = 0; k0 < 256; k0 += 16) {
        {
            int m = t >> 2, c4 = (t & 3) * 4;
            float4 av = *(const float4*)(pw + (size_t)m * 256 + k0 + c4);
            As[(c4 + 0) * 68 + m] = av.x;
            As[(c4 + 1) * 68 + m] = av.y;
            As[(c4 + 2) * 68 + m] = av.z;
            As[(c4 + 3) * 68 + m] = av.w;
        }
#pragma unroll
        for (int l = 0; l < 2; ++l) {
            int f = t + l * 256;
            int c = f >> 5, n4 = (f & 31) * 4;
            *(float4*)(Bs + c * 128 + n4) =
                *(const float4*)(B + (size_t)(k0 + c) * NPOS + n0 + n4);
        }
        __syncthreads();
#pragma unroll
        for (int kk = 0; kk < 16; ++kk) {
            float a[4], bb[8];
            *(float4*)(&a[0])  = *(const float4*)(As + kk * 68 + ty * 4);
            *(float4*)(&bb[0]) = *(const float4*)(Bs + kk * 128 + tx * 8);
            *(float4*)(&bb[4]) = *(const float4*)(Bs + kk * 128 + tx * 8 + 4);
#pragma unroll
            for (int i = 0; i < 4; ++i)
#pragma unroll
                for (int j = 0; j < 8; ++j)
                    acc[i][j] = fmaf(a[i], bb[j], acc[i][j]);
        }
        __syncthreads();
    }

    int n = n0 + tx * 8;
#pragma unroll
    for (int i = 0; i < 4; ++i) {
        int o = ty * 4 + i;
        float bias = pb[o];
        float vals[8];
#pragma unroll
        for (int j = 0; j < 8; ++j) vals[j] = acc[i][j] + bias;
        float* op = out + ((size_t)b * 64 + o) * NPOS + n;
        *(float4*)(op)     = *(float4*)(&vals[0]);
        *(float4*)(op + 4) = *(float4*)(&vals[4]);
    }
}

// ---------------------------------------------------------------------------
extern "C" void kernel_launch(void* const* d_in, const int* in_sizes, int n_in,
                              void* d_out, int out_size, void* d_ws, size_t ws_size,
                              hipStream_t stream)
{
    const float* x1   = (const float*)d_in[0];
    const float* x2   = (const float*)d_in[1];
    const float* wvis = (const float*)d_in[2];
    const float* wir  = (const float*)d_in[3];
    const float* qw   = (const float*)d_in[4];
    const float* qb   = (const float*)d_in[5];
    const float* kw   = (const float*)d_in[6];
    const float* kb   = (const float*)d_in[7];
    const float* vw   = (const float*)d_in[8];
    const float* vb   = (const float*)d_in[9];
    const float* pw   = (const float*)d_in[10];
    const float* pb   = (const float*)d_in[11];
    float* out = (float*)d_out;

    float* ws = (float*)d_ws;
    size_t F = ws_size / 4;
    size_t fixed = 350000;   // T table (24576 f32) + weights (1.18M u16)
    size_t avail = (F > fixed) ? (F - fixed) : 0;
    int G = (int)(avail / (4 * PERB));
    if (G < 1) G = 1;
    if (G > 8) G = 8;

    float* ttab  = ws;                       // 24576 floats
    float* qbuf  = ws + 24576;
    float* kbuf  = qbuf + (size_t)G * PERB;
    float* vbuf  = kbuf + (size_t)G * PERB;
    float* fbuf  = vbuf + (size_t)G * PERB;
    u16*   whiP  = (u16*)(fbuf + (size_t)G * PERB);
    u16*   wloP  = whiP + 589824;

    tt_kernel<<<dim3(96), 256, 0, stream>>>(ttab);
    wsplit<<<dim3(144), 256, 0, stream>>>(qw, kw, vw, whiP, wloP);

    for (int b0 = 0; b0 < 16; b0 += G) {
        int g = (16 - b0 < G) ? (16 - b0) : G;
        for (int s = 0; s < 3; ++s) {
            const float* sq  = (s == 0) ? (x1 + (size_t)b0 * PERB) : fbuf;
            const float* skv = (s == 0) ? (x2 + (size_t)b0 * PERB) : fbuf;
            gemm_qkv_mfma<<<dim3(3, 72, g), 512, 0, stream>>>(
                whiP + (size_t)s * 196608, wloP + (size_t)s * 196608,
                sq, skv,
                qb + (size_t)s * 256, kb + (size_t)s * 256, vb + (size_t)s * 256,
                wvis + (size_t)b0 * NPOS, wir + (size_t)b0 * NPOS,
                ttab, qbuf, kbuf, vbuf);
            attn_kernel<<<dim3(256 * g), 256, 0, stream>>>(qbuf, kbuf, vbuf, fbuf);
        }
        proj_kernel<<<dim3(72, g), 256, 0, stream>>>(
            fbuf, pw, pb, out + (size_t)b0 * 64 * NPOS);
    }
}

// Round 16
// 1575.307 us; speedup vs baseline: 1.3739x; 1.2079x over previous
//
#include <hip/hip_runtime.h>
#include <hip/hip_bf16.h>
#include <math.h>

// Shapes: B=16, C=256, H=W=96, S=3, OUT_C=64
#define NPOS 9216
#define PERB 2359296ull        // 256*9216 elements (one [C][H*W] plane-set)

typedef unsigned short u16;
typedef __attribute__((ext_vector_type(8))) short short8;  // bf16x8 MFMA frag
typedef __attribute__((ext_vector_type(4))) float f32x4;   // MFMA acc

__device__ inline u16 bfhi(float x) {
    unsigned int b = __float_as_uint(x);
    return (u16)((b + 0x7FFFu + ((b >> 16) & 1u)) >> 16);   // RNE f32->bf16
}
__device__ inline float bf2f(u16 u) { return __uint_as_float(((unsigned int)u) << 16); }

// async global->LDS, 16B per lane (dest = uniform base + lane*16)
typedef const __attribute__((address_space(1))) void* gvp;
typedef __attribute__((address_space(3))) void* lvp;
__device__ __forceinline__ void glds16(const void* g, void* l) {
    __builtin_amdgcn_global_load_lds((gvp)g, (lvp)l, 16, 0, 0);
}

// ---------------------------------------------------------------------------
// Separable positional-encoding table: T[c][p], c=4j+r.
// ---------------------------------------------------------------------------
__global__ __launch_bounds__(256) void tt_kernel(float* __restrict__ T)
{
    int idx = blockIdx.x * 256 + threadIdx.x;   // 0..24575 (256c x 96p)
    int c = idx / 96, p = idx - (idx / 96) * 96;
    int j = c >> 2, r = c & 3;
    float f = expf(-(float)(2 * j) * 0.07195578415f);  // ln(10000)/128
    float x = (float)p * (1.0f / 95.0f) * f;
    T[idx] = (r == 0) ? sinf(x) : (r == 1) ? cosf(x) : 0.0f;
}

// ---------------------------------------------------------------------------
// Weight split: W[s][mat][256][256] f32 -> blocked bf16 hi/lo, XOR-swizzled.
// layout: [s][mat*2+mb][kb][128 rows][4 slots][8] with slot ^= (row>>1)&3
// ---------------------------------------------------------------------------
__global__ __launch_bounds__(256) void wsplit(
    const float* __restrict__ qw, const float* __restrict__ kw,
    const float* __restrict__ vw, u16* __restrict__ whi, u16* __restrict__ wlo)
{
    int bid = blockIdx.x;
    int s = bid / 48, rem = bid % 48;
    int mat = rem / 16, rem2 = rem % 16;
    int mb = rem2 / 8, kb = rem2 % 8;
    const float* W = ((mat == 0) ? qw : (mat == 1) ? kw : vw) + (size_t)s * 65536;
    int t = threadIdx.x;
    int m = t >> 1, kh = (t & 1) * 16;
    const float* src = W + (size_t)(mb * 128 + m) * 256 + kb * 32 + kh;
    int s0 = kh >> 3;                  // 0 or 2
    int sw = (m >> 1) & 3;
    size_t ob = (size_t)s * 196608 + (size_t)((mat * 2 + mb) * 8 + kb) * 4096
              + (size_t)m * 32;
    u16 hv[16], lv[16];
#pragma unroll
    for (int j = 0; j < 16; ++j) {
        float x = src[j];
        u16 h = bfhi(x);
        hv[j] = h;
        lv[j] = bfhi(x - bf2f(h));
    }
    *(uint4*)(whi + ob + ((s0 ^ sw) * 8))       = *(uint4*)hv;
    *(uint4*)(whi + ob + (((s0 + 1) ^ sw) * 8)) = *(uint4*)(hv + 8);
    *(uint4*)(wlo + ob + ((s0 ^ sw) * 8))       = *(uint4*)lv;
    *(uint4*)(wlo + ob + (((s0 + 1) ^ sw) * 8)) = *(uint4*)(lv + 8);
}

// ---------------------------------------------------------------------------
// MFMA QKV GEMM (round-15 fat-M structure, unchanged).
// ---------------------------------------------------------------------------
__global__ __launch_bounds__(512, 4) void gemm_qkv_mfma(
    const u16* __restrict__ whi, const u16* __restrict__ wlo,
    const float* __restrict__ srcq, const float* __restrict__ srckv,
    const float* __restrict__ qb, const float* __restrict__ kbias,
    const float* __restrict__ vb, const float* __restrict__ wvis,
    const float* __restrict__ wir, const float* __restrict__ Ttab,
    float* __restrict__ qo, float* __restrict__ ko, float* __restrict__ vo)
{
    __shared__ char LDSBUF[49152];
    u16* AH = (u16*)LDSBUF;
    u16* AL = AH + 8192;
    u16* BH = AL + 8192;
    u16* BL = BH + 4096;

    int t = threadIdx.x;
    int d = blockIdx.x + 3 * blockIdx.y;           // 0..215
    int role = (d & 7) * 27 + (d >> 3);
    int mat = role / 72, bn = role % 72;
    int b = blockIdx.z;

    const float* gB = ((mat == 0) ? srcq : srckv) + (size_t)b * PERB + bn * 128;
    const u16* gA0 = whi + (size_t)(mat * 2) * 32768;
    const u16* gA1 = wlo + (size_t)(mat * 2) * 32768;

    int wv = t >> 6;
    int wm = wv >> 1, wn = wv & 1;
    int rr = t & 15, gq = (t >> 4) & 3;

    int sxor = (gq ^ ((rr >> 1) & 3)) * 8;
    int offA0 = (wm * 64 + rr) * 32 + sxor;
    int offB0 = (wn * 64 + rr) * 32 + sxor;

    int arow = t >> 2, acol = (t & 3) * 8;
    size_t asrc0 = (size_t)arow * 32 + acol;
    size_t asrc1 = 32768 + (size_t)arow * 32 + acol;

    int bn_ = t & 127, bkh = t >> 7;
    int key = (bn_ >> 1) & 3;
    int wrB = bn_ * 32 + ((bkh ^ key) * 8);
    const float* bp = gB + (size_t)(bkh * 8) * NPOS + bn_;

    f32x4 acc[4][4];
#pragma unroll
    for (int i = 0; i < 4; ++i)
#pragma unroll
        for (int j = 0; j < 4; ++j) acc[i][j] = (f32x4){0.f, 0.f, 0.f, 0.f};

    float xv[8];
#pragma unroll
    for (int j = 0; j < 8; ++j) xv[j] = bp[(size_t)j * NPOS];

    for (int kq = 0; kq < 8; ++kq) {
        {
            glds16(gA0 + kq * 4096 + asrc0, &AH[t * 8]);
            glds16(gA0 + kq * 4096 + asrc1, &AH[t * 8 + 4096]);
            glds16(gA1 + kq * 4096 + asrc0, &AL[t * 8]);
            glds16(gA1 + kq * 4096 + asrc1, &AL[t * 8 + 4096]);
        }
        {
            u16 hv[8], lv[8];
#pragma unroll
            for (int j = 0; j < 8; ++j) {
                float x = xv[j];
                u16 h = bfhi(x);
                hv[j] = h;
                lv[j] = bfhi(x - bf2f(h));
            }
            *(uint4*)(&BH[wrB]) = *(uint4*)hv;
            *(uint4*)(&BL[wrB]) = *(uint4*)lv;
        }
        __syncthreads();

        if (kq < 7) {
#pragma unroll
            for (int j = 0; j < 8; ++j)
                xv[j] = bp[(size_t)((kq + 1) * 32 + j) * NPOS];
        }

        short8 bh[4], bl[4];
#pragma unroll
        for (int r = 0; r < 4; ++r) {
            bh[r] = *(const short8*)(&BH[offB0 + r * 512]);
            bl[r] = *(const short8*)(&BL[offB0 + r * 512]);
        }
#pragma unroll
        for (int f = 0; f < 4; ++f) {
            short8 ah = *(const short8*)(&AH[offA0 + f * 512]);
            short8 al = *(const short8*)(&AL[offA0 + f * 512]);
#pragma unroll
            for (int r = 0; r < 4; ++r) {
                acc[f][r] = __builtin_amdgcn_mfma_f32_16x16x32_bf16(ah, bh[r], acc[f][r], 0, 0, 0);
                acc[f][r] = __builtin_amdgcn_mfma_f32_16x16x32_bf16(ah, bl[r], acc[f][r], 0, 0, 0);
                acc[f][r] = __builtin_amdgcn_mfma_f32_16x16x32_bf16(al, bh[r], acc[f][r], 0, 0, 0);
            }
        }
        asm volatile("s_waitcnt lgkmcnt(0)" ::: "memory");
        __builtin_amdgcn_s_barrier();
        __builtin_amdgcn_sched_barrier(0);
    }

    float* SB = (float*)LDSBUF + (size_t)wv * (16 * 68);
    const float* wmap = ((mat == 0) ? wvis : wir) + (size_t)b * NPOS;
    const float* bias = (mat == 0) ? qb : (mat == 1) ? kbias : vb;
    float* outp = ((mat == 0) ? qo : (mat == 1) ? ko : vo) + (size_t)b * PERB;
    bool addpe = (mat != 2);

    int lane = t & 63;
    int lrow = lane >> 2;
    int lq   = lane & 3;
    int base_n = bn * 128 + wn * 64;

#pragma unroll
    for (int f = 0; f < 4; ++f) {
#pragma unroll
        for (int r = 0; r < 4; ++r)
#pragma unroll
            for (int ri = 0; ri < 4; ++ri)
                SB[(gq * 4 + ri) * 68 + (r * 16 + rr)] = acc[f][r][ri];
        int o = wm * 64 + f * 16 + lrow;
        float bo = bias[o];
        const float* tro = Ttab + o * 96;
        float* orow = outp + (size_t)o * NPOS;
#pragma unroll
        for (int qd = 0; qd < 4; ++qd) {
            int c0 = lq * 16 + qd * 4;
            int n = base_n + c0;
            float4 v4 = *(float4*)&SB[lrow * 68 + c0];
            float4 s4 = *(const float4*)&wmap[n];
            float4 o4;
            if (addpe) {
                int hh = n / 96, ww = n - hh * 96;
                float4 pw4 = *(const float4*)&tro[ww];
                float ph = tro[hh];
                o4.x = v4.x * s4.x + bo + pw4.x + ph;
                o4.y = v4.y * s4.y + bo + pw4.y + ph;
                o4.z = v4.z * s4.z + bo + pw4.z + ph;
                o4.w = v4.w * s4.w + bo + pw4.w + ph;
            } else {
                o4.x = v4.x * s4.x + bo;
                o4.y = v4.y * s4.y + bo;
                o4.z = v4.z * s4.z + bo;
                o4.w = v4.w * s4.w + bo;
            }
            *(float4*)&orow[n] = o4;
        }
    }
}

// ---------------------------------------------------------------------------
// MFMA attention per (b,c) plane: 192 threads = 3 waves, wave owns 32 rows.
// Q,K,P,V^T stored as swizzled bf16 hi/lo kstep tiles [3][96][32] (the
// GEMM-verified layout).  4-term QK (precision), in-register softmax,
// 3-term PV, f32 LDS bounce for coalesced output.
// ---------------------------------------------------------------------------
__global__ __launch_bounds__(192, 2) void attn_mfma(
    const float* __restrict__ q, const float* __restrict__ k,
    const float* __restrict__ v, float* __restrict__ fused)
{
    __shared__ char LB[76800];
    u16* QH = (u16*)LB;                 // later PH
    u16* QL = (u16*)(LB + 19200);       // later PL
    u16* KH = (u16*)(LB + 38400);       // later VTH
    u16* KL = (u16*)(LB + 57600);       // later VTL
    float* OB = (float*)LB;             // [96][100] bounce (aliases QH/QL)

    int t = threadIdx.x;
    int bc = blockIdx.x;
    size_t base = (size_t)bc * NPOS;
    int wq = t >> 6, rr = t & 15, gq = (t >> 4) & 3;
    int sxor = (gq ^ ((rr >> 1) & 3)) * 8;

    // ---- stage Q,K ----
#pragma unroll
    for (int i = 0; i < 12; ++i) {
        int idx = i * 192 + t;
        int row = idx / 24, c4 = (idx % 24) * 4;
        int tile = c4 >> 5, kin = c4 & 31;
        int a = tile * 3072 + row * 32 + (((kin >> 3) ^ ((row >> 1) & 3)) << 3) + (kin & 7);
        float4 qv = *(const float4*)(q + base + row * 96 + c4);
        float4 kv = *(const float4*)(k + base + row * 96 + c4);
        unsigned int qh01, qh23, ql01, ql23, kh01, kh23, kl01, kl23;
        {
            u16 h0 = bfhi(qv.x), h1 = bfhi(qv.y), h2 = bfhi(qv.z), h3 = bfhi(qv.w);
            u16 l0 = bfhi(qv.x - bf2f(h0)), l1 = bfhi(qv.y - bf2f(h1));
            u16 l2 = bfhi(qv.z - bf2f(h2)), l3 = bfhi(qv.w - bf2f(h3));
            qh01 = (unsigned)h0 | ((unsigned)h1 << 16); qh23 = (unsigned)h2 | ((unsigned)h3 << 16);
            ql01 = (unsigned)l0 | ((unsigned)l1 << 16); ql23 = (unsigned)l2 | ((unsigned)l3 << 16);
        }
        {
            u16 h0 = bfhi(kv.x), h1 = bfhi(kv.y), h2 = bfhi(kv.z), h3 = bfhi(kv.w);
            u16 l0 = bfhi(kv.x - bf2f(h0)), l1 = bfhi(kv.y - bf2f(h1));
            u16 l2 = bfhi(kv.z - bf2f(h2)), l3 = bfhi(kv.w - bf2f(h3));
            kh01 = (unsigned)h0 | ((unsigned)h1 << 16); kh23 = (unsigned)h2 | ((unsigned)h3 << 16);
            kl01 = (unsigned)l0 | ((unsigned)l1 << 16); kl23 = (unsigned)l2 | ((unsigned)l3 << 16);
        }
        *(uint2*)(QH + a) = (uint2){qh01, qh23};
        *(uint2*)(QL + a) = (uint2){ql01, ql23};
        *(uint2*)(KH + a) = (uint2){kh01, kh23};
        *(uint2*)(KL + a) = (uint2){kl01, kl23};
    }
    __syncthreads();

    // ---- QK^T (4-term split) ----
    f32x4 acc[2][6];
#pragma unroll
    for (int mt = 0; mt < 2; ++mt)
#pragma unroll
        for (int nt = 0; nt < 6; ++nt) acc[mt][nt] = (f32x4){0.f, 0.f, 0.f, 0.f};

#pragma unroll
    for (int ks = 0; ks < 3; ++ks) {
        short8 qh2[2], ql2[2], kh6[6], kl6[6];
#pragma unroll
        for (int mt = 0; mt < 2; ++mt) {
            int ra = ks * 3072 + (wq * 32 + mt * 16 + rr) * 32 + sxor;
            qh2[mt] = *(const short8*)(QH + ra);
            ql2[mt] = *(const short8*)(QL + ra);
        }
#pragma unroll
        for (int nt = 0; nt < 6; ++nt) {
            int rb = ks * 3072 + (nt * 16 + rr) * 32 + sxor;
            kh6[nt] = *(const short8*)(KH + rb);
            kl6[nt] = *(const short8*)(KL + rb);
        }
#pragma unroll
        for (int mt = 0; mt < 2; ++mt)
#pragma unroll
            for (int nt = 0; nt < 6; ++nt) {
                acc[mt][nt] = __builtin_amdgcn_mfma_f32_16x16x32_bf16(qh2[mt], kh6[nt], acc[mt][nt], 0, 0, 0);
                acc[mt][nt] = __builtin_amdgcn_mfma_f32_16x16x32_bf16(qh2[mt], kl6[nt], acc[mt][nt], 0, 0, 0);
                acc[mt][nt] = __builtin_amdgcn_mfma_f32_16x16x32_bf16(ql2[mt], kh6[nt], acc[mt][nt], 0, 0, 0);
                acc[mt][nt] = __builtin_amdgcn_mfma_f32_16x16x32_bf16(ql2[mt], kl6[nt], acc[mt][nt], 0, 0, 0);
            }
    }

    // ---- softmax over g (row = wq*32 + mt*16 + gq*4 + ri; 16 rr lanes/row) ----
#pragma unroll
    for (int mt = 0; mt < 2; ++mt)
#pragma unroll
        for (int ri = 0; ri < 4; ++ri) {
            float mx = acc[mt][0][ri];
#pragma unroll
            for (int nt = 1; nt < 6; ++nt) mx = fmaxf(mx, acc[mt][nt][ri]);
            for (int dd = 1; dd < 16; dd <<= 1) mx = fmaxf(mx, __shfl_xor(mx, dd));
            float s = 0.0f;
#pragma unroll
            for (int nt = 0; nt < 6; ++nt) {
                float e = __expf(acc[mt][nt][ri] - mx);
                acc[mt][nt][ri] = e;
                s += e;
            }
            for (int dd = 1; dd < 16; dd <<= 1) s += __shfl_xor(s, dd);
            float inv = 1.0f / s;
#pragma unroll
            for (int nt = 0; nt < 6; ++nt) acc[mt][nt][ri] *= inv;
        }

    __syncthreads();   // QK reads of QH/QL/KH/KL done block-wide

    // ---- write P (into Q regions) + stage V^T (into K regions) ----
#pragma unroll
    for (int mt = 0; mt < 2; ++mt)
#pragma unroll
        for (int ri = 0; ri < 4; ++ri) {
            int row = wq * 32 + mt * 16 + gq * 4 + ri;
            int keyr = (row >> 1) & 3;
#pragma unroll
            for (int nt = 0; nt < 6; ++nt) {
                float val = acc[mt][nt][ri];
                u16 h = bfhi(val);
                u16 l = bfhi(val - bf2f(h));
                int slot = ((nt & 1) << 1) | (rr >> 3);
                int a = (nt >> 1) * 3072 + row * 32 + ((slot ^ keyr) << 3) + (rr & 7);
                QH[a] = h;   // PH
                QL[a] = l;   // PL
            }
        }
#pragma unroll
    for (int i = 0; i < 12; ++i) {
        int idx = i * 192 + t;
        int grow = idx / 24, c4 = (idx % 24) * 4;
        float4 vv = *(const float4*)(v + base + grow * 96 + c4);
        int tile = grow >> 5, kin = grow & 31;
        int slot = kin >> 3, off = kin & 7;
#pragma unroll
        for (int e = 0; e < 4; ++e) {
            int w = c4 + e;
            float val = (e == 0) ? vv.x : (e == 1) ? vv.y : (e == 2) ? vv.z : vv.w;
            u16 h = bfhi(val);
            u16 l = bfhi(val - bf2f(h));
            int a = tile * 3072 + w * 32 + ((slot ^ ((w >> 1) & 3)) << 3) + off;
            KH[a] = h;   // VTH
            KL[a] = l;   // VTL
        }
    }
    __syncthreads();

    // ---- PV (3-term split) ----
#pragma unroll
    for (int mt = 0; mt < 2; ++mt)
#pragma unroll
        for (int nt = 0; nt < 6; ++nt) acc[mt][nt] = (f32x4){0.f, 0.f, 0.f, 0.f};

#pragma unroll
    for (int ks = 0; ks < 3; ++ks) {
        short8 ph2[2], pl2[2], vh6[6], vl6[6];
#pragma unroll
        for (int mt = 0; mt < 2; ++mt) {
            int ra = ks * 3072 + (wq * 32 + mt * 16 + rr) * 32 + sxor;
            ph2[mt] = *(const short8*)(QH + ra);
            pl2[mt] = *(const short8*)(QL + ra);
        }
#pragma unroll
        for (int nt = 0; nt < 6; ++nt) {
            int rb = ks * 3072 + (nt * 16 + rr) * 32 + sxor;
            vh6[nt] = *(const short8*)(KH + rb);
            vl6[nt] = *(const short8*)(KL + rb);
        }
#pragma unroll
        for (int mt = 0; mt < 2; ++mt)
#pragma unroll
            for (int nt = 0; nt < 6; ++nt) {
                acc[mt][nt] = __builtin_amdgcn_mfma_f32_16x16x32_bf16(ph2[mt], vh6[nt], acc[mt][nt], 0, 0, 0);
                acc[mt][nt] = __builtin_amdgcn_mfma_f32_16x16x32_bf16(ph2[mt], vl6[nt], acc[mt][nt], 0, 0, 0);
                acc[mt][nt] = __builtin_amdgcn_mfma_f32_16x16x32_bf16(pl2[mt], vh6[nt], acc[mt][nt], 0, 0, 0);
            }
    }
    __syncthreads();   // PV reads done before OB overwrites P regions

    // ---- f32 bounce + coalesced output ----
#pragma unroll
    for (int mt = 0; mt < 2; ++mt)
#pragma unroll
        for (int nt = 0; nt < 6; ++nt)
#pragma unroll
            for (int ri = 0; ri < 4; ++ri) {
                int row = wq * 32 + mt * 16 + gq * 4 + ri;
                OB[row * 100 + nt * 16 + rr] = acc[mt][nt][ri];
            }
    __syncthreads();
#pragma unroll
    for (int i = 0; i < 12; ++i) {
        int idx = i * 192 + t;
        int row = idx / 24, c4 = (idx % 24) * 4;
        float4 o = *(const float4*)&OB[row * 100 + c4];
        *(float4*)(fused + base + row * 96 + c4) = o;
    }
}

// ---------------------------------------------------------------------------
// Final projection: out[b][o][n] = sum_c proj_w[o][c]*fused[b][c][n] + pb[o]
// ---------------------------------------------------------------------------
__global__ __launch_bounds__(256) void proj_kernel(
    const float* __restrict__ fused, const float* __restrict__ pw,
    const float* __restrict__ pb, float* __restrict__ out)
{
    __shared__ float As[16 * 68];
    __shared__ float Bs[16 * 128];

    int t  = threadIdx.x;
    int n0 = blockIdx.x * 128;
    int b  = blockIdx.y;
    const float* B = fused + (size_t)b * PERB;
    int tx = t & 15, ty = t >> 4;

    float acc[4][8];
#pragma unroll
    for (int i = 0; i < 4; ++i)
#pragma unroll
        for (int j = 0; j < 8; ++j) acc[i][j] = 0.0f;

    for (int k0 = 0; k0 < 256; k0 += 16) {
        {
            int m = t >> 2, c4 = (t & 3) * 4;
            float4 av = *(const float4*)(pw + (size_t)m * 256 + k0 + c4);
            As[(c4 + 0) * 68 + m] = av.x;
            As[(c4 + 1) * 68 + m] = av.y;
            As[(c4 + 2) * 68 + m] = av.z;
            As[(c4 + 3) * 68 + m] = av.w;
        }
#pragma unroll
        for (int l = 0; l < 2; ++l) {
            int f = t + l * 256;
            int c = f >> 5, n4 = (f & 31) * 4;
            *(float4*)(Bs + c * 128 + n4) =
                *(const float4*)(B + (size_t)(k0 + c) * NPOS + n0 + n4);
        }
        __syncthreads();
#pragma unroll
        for (int kk = 0; kk < 16; ++kk) {
            float a[4], bb[8];
            *(float4*)(&a[0])  = *(const float4*)(As + kk * 68 + ty * 4);
            *(float4*)(&bb[0]) = *(const float4*)(Bs + kk * 128 + tx * 8);
            *(float4*)(&bb[4]) = *(const float4*)(Bs + kk * 128 + tx * 8 + 4);
#pragma unroll
            for (int i = 0; i < 4; ++i)
#pragma unroll
                for (int j = 0; j < 8; ++j)
                    acc[i][j] = fmaf(a[i], bb[j], acc[i][j]);
        }
        __syncthreads();
    }

    int n = n0 + tx * 8;
#pragma unroll
    for (int i = 0; i < 4; ++i) {
        int o = ty * 4 + i;
        float bias = pb[o];
        float vals[8];
#pragma unroll
        for (int j = 0; j < 8; ++j) vals[j] = acc[i][j] + bias;
        float* op = out + ((size_t)b * 64 + o) * NPOS + n;
        *(float4*)(op)     = *(float4*)(&vals[0]);
        *(float4*)(op + 4) = *(float4*)(&vals[4]);
    }
}

// ---------------------------------------------------------------------------
extern "C" void kernel_launch(void* const* d_in, const int* in_sizes, int n_in,
                              void* d_out, int out_size, void* d_ws, size_t ws_size,
                              hipStream_t stream)
{
    const float* x1   = (const float*)d_in[0];
    const float* x2   = (const float*)d_in[1];
    const float* wvis = (const float*)d_in[2];
    const float* wir  = (const float*)d_in[3];
    const float* qw   = (const float*)d_in[4];
    const float* qb   = (const float*)d_in[5];
    const float* kw   = (const float*)d_in[6];
    const float* kb   = (const float*)d_in[7];
    const float* vw   = (const float*)d_in[8];
    const float* vb   = (const float*)d_in[9];
    const float* pw   = (const float*)d_in[10];
    const float* pb   = (const float*)d_in[11];
    float* out = (float*)d_out;

    float* ws = (float*)d_ws;
    size_t F = ws_size / 4;
    size_t fixed = 350000;
    size_t avail = (F > fixed) ? (F - fixed) : 0;
    int G = (int)(avail / (4 * PERB));
    if (G < 1) G = 1;
    if (G > 8) G = 8;

    float* ttab  = ws;
    float* qbuf  = ws + 24576;
    float* kbuf  = qbuf + (size_t)G * PERB;
    float* vbuf  = kbuf + (size_t)G * PERB;
    float* fbuf  = vbuf + (size_t)G * PERB;
    u16*   whiP  = (u16*)(fbuf + (size_t)G * PERB);
    u16*   wloP  = whiP + 589824;

    tt_kernel<<<dim3(96), 256, 0, stream>>>(ttab);
    wsplit<<<dim3(144), 256, 0, stream>>>(qw, kw, vw, whiP, wloP);

    for (int b0 = 0; b0 < 16; b0 += G) {
        int g = (16 - b0 < G) ? (16 - b0) : G;
        for (int s = 0; s < 3; ++s) {
            const float* sq  = (s == 0) ? (x1 + (size_t)b0 * PERB) : fbuf;
            const float* skv = (s == 0) ? (x2 + (size_t)b0 * PERB) : fbuf;
            gemm_qkv_mfma<<<dim3(3, 72, g), 512, 0, stream>>>(
                whiP + (size_t)s * 196608, wloP + (size_t)s * 196608,
                sq, skv,
                qb + (size_t)s * 256, kb + (size_t)s * 256, vb + (size_t)s * 256,
                wvis + (size_t)b0 * NPOS, wir + (size_t)b0 * NPOS,
                ttab, qbuf, kbuf, vbuf);
            attn_mfma<<<dim3(256 * g), 192, 0, stream>>>(qbuf, kbuf, vbuf, fbuf);
        }
        proj_kernel<<<dim3(72, g), 256, 0, stream>>>(
            fbuf, pw, pb, out + (size_t)b0 * 64 * NPOS);
    }
}